// Round 4
// baseline (205.761 us; speedup 1.0000x reference)
//
#include <hip/hip_runtime.h>

typedef float f32x4 __attribute__((ext_vector_type(4)));
typedef __bf16 bf16x8 __attribute__((ext_vector_type(8)));

#define D_MODEL 1024
#define SEQ     2048
#define NB      2
#define NH      16
#define DK      64

__device__ __forceinline__ unsigned short f2bf(float f) {
    union { float f; unsigned int u; } un; un.f = f;
    unsigned int r = un.u + 0x7fffu + ((un.u >> 16) & 1u);
    return (unsigned short)(r >> 16);
}

__device__ __forceinline__ void gload16(const void* g, void* l) {
    __builtin_amdgcn_global_load_lds((__attribute__((address_space(1))) void*)g,
                                     (__attribute__((address_space(3))) void*)l,
                                     16, 0, 0);
}

// ---------------------------------------------------------------------------
// fused fp32 -> bf16 casts for x and the 4 weights + RoPE cos/sin table
// ---------------------------------------------------------------------------
__global__ __launch_bounds__(256) void cast5(
    const float* __restrict__ x,  const float* __restrict__ wq,
    const float* __restrict__ wk, const float* __restrict__ wv,
    const float* __restrict__ wo,
    unsigned short* __restrict__ xb,  unsigned short* __restrict__ wqb,
    unsigned short* __restrict__ wkb, unsigned short* __restrict__ wvb,
    unsigned short* __restrict__ wob, float2* __restrict__ tab)
{
    if (blockIdx.y == 5) {  // RoPE table: [ss][p] -> (cos, sin), p = d/2 index
        int idx = blockIdx.x * 256 + threadIdx.x;
        if (idx < SEQ * 32) {
            int ss = idx >> 5, p = idx & 31;
            float freq = exp2f(-0.41524101186f * (float)p);  // 10000^(-p/32)
            float sn, cs;
            sincosf((float)ss * freq, &sn, &cs);
            tab[idx] = make_float2(cs, sn);
        }
        return;
    }
    const float* src; unsigned short* dst; int n8;
    switch (blockIdx.y) {
        case 0:  src = x;  dst = xb;  n8 = (NB*SEQ*D_MODEL)/8; break;
        case 1:  src = wq; dst = wqb; n8 = (D_MODEL*D_MODEL)/8; break;
        case 2:  src = wk; dst = wkb; n8 = (D_MODEL*D_MODEL)/8; break;
        case 3:  src = wv; dst = wvb; n8 = (D_MODEL*D_MODEL)/8; break;
        default: src = wo; dst = wob; n8 = (D_MODEL*D_MODEL)/8; break;
    }
    int stride = gridDim.x * blockDim.x;
    for (int i = blockIdx.x * blockDim.x + threadIdx.x; i < n8; i += stride) {
        const float4* p = (const float4*)src + (size_t)i * 2;
        float4 a = p[0], b = p[1];
        union { unsigned short h[8]; uint4 v; } u;
        u.h[0] = f2bf(a.x); u.h[1] = f2bf(a.y); u.h[2] = f2bf(a.z); u.h[3] = f2bf(a.w);
        u.h[4] = f2bf(b.x); u.h[5] = f2bf(b.y); u.h[6] = f2bf(b.z); u.h[7] = f2bf(b.w);
        ((uint4*)dst)[i] = u.v;
    }
}

// ---------------------------------------------------------------------------
// GEMM  C[M][1024] = A[M][K](bf16) * B[1024][K]^T (bf16, weights are [out][in])
// MODE 0: plain fp32 write to outF
// MODE 1: QKV fused: RoPE via table on Q(z=0, scaled by 0.125*log2e for
//   exp2-domain softmax) and K(z=1) -> [bh][s][64]; V(z=2) -> [bh][64][s].
//   Epilogue staged through LDS for full-128B-line stores.
// ---------------------------------------------------------------------------
template <int MODE>
__global__ __launch_bounds__(256) void gemm_bt(
    const unsigned short* __restrict__ A,
    const unsigned short* __restrict__ B0,
    const unsigned short* __restrict__ B1,
    const unsigned short* __restrict__ B2,
    float* __restrict__ outF,
    unsigned short* __restrict__ Qh,
    unsigned short* __restrict__ Kh,
    unsigned short* __restrict__ Vt,
    const float2* __restrict__ tab,
    int M, int K)
{
    __shared__ unsigned short As[128 * 32];
    __shared__ unsigned short Bs[128 * 32];

    const int lane = threadIdx.x & 63;
    const int wid  = threadIdx.x >> 6;
    const int l15 = lane & 15, lhi = lane >> 4;
    const int m0 = blockIdx.y * 128;
    const int n0 = blockIdx.x * 128;
    const int z  = (MODE == 1) ? (int)blockIdx.z : 0;
    const unsigned short* B = (z == 0) ? B0 : (z == 1) ? B1 : B2;
    const int waveM = (wid >> 1) * 64;
    const int waveN = (wid & 1) * 64;

    f32x4 acc[4][4];
    f32x4 zero = {0.f, 0.f, 0.f, 0.f};
#pragma unroll
    for (int m = 0; m < 4; ++m)
#pragma unroll
        for (int n = 0; n < 4; ++n) acc[m][n] = zero;

    const int lrow = lane >> 2;
    const int lcol = (lane & 3) * 8;

    for (int k0 = 0; k0 < K; k0 += 32) {
#pragma unroll
        for (int q = 0; q < 2; ++q) {
            int rbase = wid * 32 + q * 16;
            const unsigned short* gA = A + (size_t)(m0 + rbase + lrow) * K + k0 + lcol;
            gload16(gA, (char*)As + rbase * 64);
            const unsigned short* gB = B + (size_t)(n0 + rbase + lrow) * K + k0 + lcol;
            gload16(gB, (char*)Bs + rbase * 64);
        }
        __syncthreads();
        bf16x8 af[4], bfr[4];
#pragma unroll
        for (int m = 0; m < 4; ++m)
            af[m] = *(const bf16x8*)(As + (waveM + m * 16 + l15) * 32 + lhi * 8);
#pragma unroll
        for (int n = 0; n < 4; ++n)
            bfr[n] = *(const bf16x8*)(Bs + (waveN + n * 16 + l15) * 32 + lhi * 8);
#pragma unroll
        for (int m = 0; m < 4; ++m)
#pragma unroll
            for (int n = 0; n < 4; ++n)
                acc[m][n] = __builtin_amdgcn_mfma_f32_16x16x32_bf16(af[m], bfr[n], acc[m][n], 0, 0, 0);
        __syncthreads();
    }

    if constexpr (MODE == 0) {
#pragma unroll
        for (int n = 0; n < 4; ++n) {
            int col = n0 + waveN + n * 16 + l15;
#pragma unroll
            for (int m = 0; m < 4; ++m) {
                int rowb = m0 + waveM + m * 16 + (lhi << 2);
#pragma unroll
                for (int r = 0; r < 4; ++r)
                    outF[(size_t)(rowb + r) * D_MODEL + col] = acc[m][n][r];
            }
        }
    } else {
        __shared__ unsigned short Ct[4][64][72];
        const int colg0 = n0 + waveN;
        const int hh    = (colg0 >> 6) & (NH - 1);
        const int rowg0 = m0 + waveM;
        const int bb    = rowg0 >> 11;
        const size_t bhh = (size_t)(bb * NH + hh);

#pragma unroll
        for (int n = 0; n < 4; ++n) {
            int cl = n * 16 + l15;
#pragma unroll
            for (int m = 0; m < 4; ++m) {
#pragma unroll
                for (int r = 0; r < 4; ++r) {
                    float v  = acc[m][n][r];
                    float pv = __shfl_xor(v, 1);
                    int rl = m * 16 + (lhi << 2) + r;
                    if (z == 2) {
                        Ct[wid][cl][rl] = f2bf(v);
                    } else {
                        int ss = (rowg0 + rl) & (SEQ - 1);
                        float2 cs = tab[(ss << 5) + (cl >> 1)];
                        float o = (cl & 1) ? (pv * cs.y + v * cs.x)
                                           : (v * cs.x - pv * cs.y);
                        if (z == 0) o *= 0.18033688011f;  // (1/8)*log2(e): exp2-domain softmax
                        Ct[wid][rl][cl] = f2bf(o);
                    }
                }
            }
        }
        asm volatile("s_waitcnt lgkmcnt(0)" ::: "memory");

        const int lr = lane >> 3;
        const int lc = (lane & 7) << 3;
#pragma unroll
        for (int i = 0; i < 8; ++i) {
            int rl = i * 8 + lr;
            uint4 w = *(const uint4*)&Ct[wid][rl][lc];
            if (z == 2) {
                int ss0 = rowg0 & (SEQ - 1);
                *(uint4*)(Vt + (bhh * DK + rl) * SEQ + ss0 + lc) = w;
            } else {
                int ss = (rowg0 + rl) & (SEQ - 1);
                unsigned short* dst = (z == 0) ? Qh : Kh;
                *(uint4*)(dst + (bhh * SEQ + ss) * DK + lc) = w;
            }
        }
    }
}

// ---------------------------------------------------------------------------
// causal flash attention v3: swapped QK^T (s = mfma(K, Q)) so each thread
// holds a full 32-value slice of ONE q-row (col=lane&15 = q-row):
//   - row max/sum = local VALU tree + 2 shfls (was 16+16 dependent shfls)
//   - softmax state m,l = 1 scalar/thread
//   - P-write = 8x ds_write_b64 (was 32x b16)
// exp2-domain (Q pre-scaled by 0.125*log2e), defer-max THR=8 (T13).
// alpha/inv moved to output-row space via 4 parallel shfls.
// ---------------------------------------------------------------------------
__global__ __launch_bounds__(256) void attn_kernel(
    const unsigned short* __restrict__ Qh,
    const unsigned short* __restrict__ Kh,
    const unsigned short* __restrict__ Vt,
    unsigned short* __restrict__ O)
{
    __shared__ unsigned short P[4][16][136];  // [wave][q-local][k 0..127], 272B stride
    const int lane = threadIdx.x & 63;
    const int wid  = threadIdx.x >> 6;
    const int bh = blockIdx.x;
    const int qt = (int)gridDim.y - 1 - (int)blockIdx.y;  // longest tiles first
    const int b = bh >> 4, h = bh & 15;
    const int q0 = qt * 64;
    const int qw = q0 + wid * 16;
    const int ktlast = (q0 + 63) >> 7;
    const int l15 = lane & 15, lhi = lane >> 4;

    const unsigned short* Qb = Qh + (size_t)bh * SEQ * DK;
    const unsigned short* Kb = Kh + (size_t)bh * SEQ * DK;
    const unsigned short* Vb = Vt + (size_t)bh * DK * SEQ;

    bf16x8 qf[2];
#pragma unroll
    for (int kk = 0; kk < 2; ++kk)
        qf[kk] = *(const bf16x8*)(Qb + (size_t)(qw + l15) * DK + kk * 32 + lhi * 8);

    const f32x4 zero = {0.f, 0.f, 0.f, 0.f};
    const f32x4 ninf = {-1e30f, -1e30f, -1e30f, -1e30f};
    f32x4 oacc[4];
#pragma unroll
    for (int nd = 0; nd < 4; ++nd) oacc[nd] = zero;
    float mrow = -1e30f;   // running max for q-row (qw + l15), log2 domain
    float lrow = 0.f;      // running denom for q-row (qw + l15)

    for (int kt = 0; kt <= ktlast; ++kt) {
        const int kv0 = kt << 7;
        const bool diag = (kt == ktlast);
        const int nlim = diag ? (((qw - kv0) >> 4) + 1) : 8;

        f32x4 s[8];  // s[n][r]: S^T -> k = kv0+n*16+(lhi<<2)+r, q = qw+l15
#pragma unroll
        for (int n = 0; n < 8; ++n) s[n] = (n < nlim) ? zero : ninf;

        // ---- QK^T swapped: A = K-frag, B = Q-frag ----
#pragma unroll
        for (int half = 0; half < 2; ++half) {
            bf16x8 kf[4][2];
#pragma unroll
            for (int n4 = 0; n4 < 4; ++n4) {
                int n = half * 4 + n4;
                if (n < nlim) {
#pragma unroll
                    for (int kk = 0; kk < 2; ++kk)
                        kf[n4][kk] = *(const bf16x8*)(Kb + (size_t)(kv0 + n * 16 + l15) * DK + kk * 32 + lhi * 8);
                }
            }
            __builtin_amdgcn_s_setprio(1);
#pragma unroll
            for (int n4 = 0; n4 < 4; ++n4) {
                int n = half * 4 + n4;
                if (n < nlim) {
#pragma unroll
                    for (int kk = 0; kk < 2; ++kk)
                        s[n] = __builtin_amdgcn_mfma_f32_16x16x32_bf16(kf[n4][kk], qf[kk], s[n], 0, 0, 0);
                }
            }
            __builtin_amdgcn_s_setprio(0);
        }

        if (diag) {  // causal: mask k > q
            const int qg = qw + l15;
#pragma unroll
            for (int n = 0; n < 8; ++n) {
                if (n < nlim) {
#pragma unroll
                    for (int r = 0; r < 4; ++r) {
                        int kg = kv0 + n * 16 + (lhi << 2) + r;
                        if (kg > qg) s[n][r] = -1e30f;
                    }
                }
            }
        }

        // ---- row max: local tree + 2 shfls ----
        float mx0 = fmaxf(fmaxf(s[0][0], s[0][1]), fmaxf(s[0][2], s[0][3]));
        float mx1 = fmaxf(fmaxf(s[1][0], s[1][1]), fmaxf(s[1][2], s[1][3]));
        float mx2 = fmaxf(fmaxf(s[2][0], s[2][1]), fmaxf(s[2][2], s[2][3]));
        float mx3 = fmaxf(fmaxf(s[3][0], s[3][1]), fmaxf(s[3][2], s[3][3]));
        float mx4 = fmaxf(fmaxf(s[4][0], s[4][1]), fmaxf(s[4][2], s[4][3]));
        float mx5 = fmaxf(fmaxf(s[5][0], s[5][1]), fmaxf(s[5][2], s[5][3]));
        float mx6 = fmaxf(fmaxf(s[6][0], s[6][1]), fmaxf(s[6][2], s[6][3]));
        float mx7 = fmaxf(fmaxf(s[7][0], s[7][1]), fmaxf(s[7][2], s[7][3]));
        float mx = fmaxf(fmaxf(fmaxf(mx0, mx1), fmaxf(mx2, mx3)),
                         fmaxf(fmaxf(mx4, mx5), fmaxf(mx6, mx7)));
        mx = fmaxf(mx, __shfl_xor(mx, 16));
        mx = fmaxf(mx, __shfl_xor(mx, 32));

        // ---- defer-max (THR = 8 in log2 domain) ----
        float alpha = 1.f;
        const int allDefer = __all(mx <= mrow + 8.f);
        if (!allDefer) {
            float mn = fmaxf(mrow, mx);
            alpha = __builtin_amdgcn_exp2f(mrow - mn);
            mrow = mn;
        }

        // ---- P = exp2(S - m) ----
#pragma unroll
        for (int n = 0; n < 8; ++n)
#pragma unroll
            for (int r = 0; r < 4; ++r)
                s[n][r] = __builtin_amdgcn_exp2f(s[n][r] - mrow);

        // ---- row sum: local tree + 2 shfls ----
        float rs = 0.f;
#pragma unroll
        for (int n = 0; n < 8; ++n)
            rs += (s[n][0] + s[n][1]) + (s[n][2] + s[n][3]);
        rs += __shfl_xor(rs, 16);
        rs += __shfl_xor(rs, 32);
        lrow = allDefer ? (lrow + rs) : (lrow * alpha + rs);

        // ---- P -> LDS: 8x ds_write_b64 (4 contiguous k per thread) ----
#pragma unroll
        for (int n = 0; n < 8; ++n) {
            union { unsigned short h[4]; uint2 v; } pk;
#pragma unroll
            for (int r = 0; r < 4; ++r) pk.h[r] = f2bf(s[n][r]);
            *(uint2*)&P[wid][l15][n * 16 + (lhi << 2)] = pk.v;
        }

        // ---- V loads issued before the LDS wait ----
        const int kklim = diag ? ((nlim + 1) >> 1) : 4;
        bf16x8 vf[4][4];  // [kk][nd]
#pragma unroll
        for (int kk = 0; kk < 4; ++kk) {
            if (kk < kklim) {
#pragma unroll
                for (int nd = 0; nd < 4; ++nd)
                    vf[kk][nd] = *(const bf16x8*)(Vb + (size_t)(nd * 16 + l15) * SEQ + kv0 + kk * 32 + lhi * 8);
            }
        }

        // ---- rescale oacc (output-row space alpha via 4 parallel shfls) ----
        if (!allDefer) {
            float a0 = __shfl(alpha, (lhi << 2) + 0);
            float a1 = __shfl(alpha, (lhi << 2) + 1);
            float a2 = __shfl(alpha, (lhi << 2) + 2);
            float a3 = __shfl(alpha, (lhi << 2) + 3);
#pragma unroll
            for (int nd = 0; nd < 4; ++nd) {
                oacc[nd][0] *= a0; oacc[nd][1] *= a1;
                oacc[nd][2] *= a2; oacc[nd][3] *= a3;
            }
        }

        asm volatile("s_waitcnt lgkmcnt(0)" ::: "memory");
        bf16x8 pa[4];
#pragma unroll
        for (int kk = 0; kk < 4; ++kk)
            if (kk < kklim)
                pa[kk] = *(const bf16x8*)(&P[wid][l15][kk * 32 + lhi * 8]);

        __builtin_amdgcn_s_setprio(1);
#pragma unroll
        for (int nd = 0; nd < 4; ++nd)
#pragma unroll
            for (int kk = 0; kk < 4; ++kk)
                if (kk < kklim)
                    oacc[nd] = __builtin_amdgcn_mfma_f32_16x16x32_bf16(pa[kk], vf[kk][nd], oacc[nd], 0, 0, 0);
        __builtin_amdgcn_s_setprio(0);
    }

    float inv = 1.f / lrow;
    float i0 = __shfl(inv, (lhi << 2) + 0);
    float i1 = __shfl(inv, (lhi << 2) + 1);
    float i2 = __shfl(inv, (lhi << 2) + 2);
    float i3 = __shfl(inv, (lhi << 2) + 3);
#pragma unroll
    for (int nd = 0; nd < 4; ++nd) {
        int d = nd * 16 + l15;
        int rowb = qw + (lhi << 2);
        O[((size_t)(b * SEQ + rowb + 0)) * D_MODEL + h * DK + d] = f2bf(oacc[nd][0] * i0);
        O[((size_t)(b * SEQ + rowb + 1)) * D_MODEL + h * DK + d] = f2bf(oacc[nd][1] * i1);
        O[((size_t)(b * SEQ + rowb + 2)) * D_MODEL + h * DK + d] = f2bf(oacc[nd][2] * i2);
        O[((size_t)(b * SEQ + rowb + 3)) * D_MODEL + h * DK + d] = f2bf(oacc[nd][3] * i3);
    }
}

// ---------------------------------------------------------------------------
extern "C" void kernel_launch(void* const* d_in, const int* in_sizes, int n_in,
                              void* d_out, int out_size, void* d_ws, size_t ws_size,
                              hipStream_t stream)
{
    const float* x  = (const float*)d_in[0];
    const float* Wq = (const float*)d_in[1];
    const float* Wk = (const float*)d_in[2];
    const float* Wv = (const float*)d_in[3];
    const float* Wo = (const float*)d_in[4];
    float* out = (float*)d_out;

    char* ws = (char*)d_ws;
    unsigned short* xb  = (unsigned short*)(ws);                    // 8 MB (reused as attn buf)
    unsigned short* Wqb = (unsigned short*)(ws + ( 8ull << 20));
    unsigned short* Wkb = (unsigned short*)(ws + (10ull << 20));
    unsigned short* Wvb = (unsigned short*)(ws + (12ull << 20));
    unsigned short* Wob = (unsigned short*)(ws + (14ull << 20));
    unsigned short* Qh  = (unsigned short*)(ws + (16ull << 20));    // [bh][s][64]
    unsigned short* Kh  = (unsigned short*)(ws + (24ull << 20));    // [bh][s][64]
    unsigned short* Vt  = (unsigned short*)(ws + (32ull << 20));    // [bh][64][s]
    float2*         tab = (float2*)(ws + (40ull << 20));            // 512 KB RoPE table
    unsigned short* attn = xb;

    cast5<<<dim3(512, 6), 256, 0, stream>>>(x, Wq, Wk, Wv, Wo, xb, Wqb, Wkb, Wvb, Wob, tab);

    gemm_bt<1><<<dim3(D_MODEL / 128, (NB * SEQ) / 128, 3), 256, 0, stream>>>(
        xb, Wqb, Wkb, Wvb, nullptr, Qh, Kh, Vt, tab, NB * SEQ, D_MODEL);

    attn_kernel<<<dim3(NB * NH, SEQ / 64), 256, 0, stream>>>(Qh, Kh, Vt, attn);

    gemm_bt<0><<<dim3(D_MODEL / 128, (NB * SEQ) / 128, 1), 256, 0, stream>>>(
        attn, Wob, Wob, Wob, out, nullptr, nullptr, nullptr, nullptr, NB * SEQ, D_MODEL);
}

// Round 5
// 183.330 us; speedup vs baseline: 1.1224x; 1.1224x over previous
//
#include <hip/hip_runtime.h>

typedef float f32x4 __attribute__((ext_vector_type(4)));
typedef __bf16 bf16x8 __attribute__((ext_vector_type(8)));

#define D_MODEL 1024
#define SEQ     2048
#define NB      2
#define NH      16
#define DK      64

__device__ __forceinline__ unsigned short f2bf(float f) {
    union { float f; unsigned int u; } un; un.f = f;
    unsigned int r = un.u + 0x7fffu + ((un.u >> 16) & 1u);
    return (unsigned short)(r >> 16);
}

__device__ __forceinline__ void gload16(const void* g, void* l) {
    __builtin_amdgcn_global_load_lds((__attribute__((address_space(1))) void*)g,
                                     (__attribute__((address_space(3))) void*)l,
                                     16, 0, 0);
}

// ---------------------------------------------------------------------------
// fused fp32 -> bf16 casts for x and the 4 weights + RoPE cos/sin table
// ---------------------------------------------------------------------------
__global__ __launch_bounds__(256) void cast5(
    const float* __restrict__ x,  const float* __restrict__ wq,
    const float* __restrict__ wk, const float* __restrict__ wv,
    const float* __restrict__ wo,
    unsigned short* __restrict__ xb,  unsigned short* __restrict__ wqb,
    unsigned short* __restrict__ wkb, unsigned short* __restrict__ wvb,
    unsigned short* __restrict__ wob, float2* __restrict__ tab)
{
    if (blockIdx.y == 5) {  // RoPE table: [ss][p] -> (cos, sin), p = d/2 index
        int idx = blockIdx.x * 256 + threadIdx.x;
        if (idx < SEQ * 32) {
            int ss = idx >> 5, p = idx & 31;
            float freq = exp2f(-0.41524101186f * (float)p);  // 10000^(-p/32)
            float sn, cs;
            sincosf((float)ss * freq, &sn, &cs);
            tab[idx] = make_float2(cs, sn);
        }
        return;
    }
    const float* src; unsigned short* dst; int n8;
    switch (blockIdx.y) {
        case 0:  src = x;  dst = xb;  n8 = (NB*SEQ*D_MODEL)/8; break;
        case 1:  src = wq; dst = wqb; n8 = (D_MODEL*D_MODEL)/8; break;
        case 2:  src = wk; dst = wkb; n8 = (D_MODEL*D_MODEL)/8; break;
        case 3:  src = wv; dst = wvb; n8 = (D_MODEL*D_MODEL)/8; break;
        default: src = wo; dst = wob; n8 = (D_MODEL*D_MODEL)/8; break;
    }
    int stride = gridDim.x * blockDim.x;
    for (int i = blockIdx.x * blockDim.x + threadIdx.x; i < n8; i += stride) {
        const float4* p = (const float4*)src + (size_t)i * 2;
        float4 a = p[0], b = p[1];
        union { unsigned short h[8]; uint4 v; } u;
        u.h[0] = f2bf(a.x); u.h[1] = f2bf(a.y); u.h[2] = f2bf(a.z); u.h[3] = f2bf(a.w);
        u.h[4] = f2bf(b.x); u.h[5] = f2bf(b.y); u.h[6] = f2bf(b.z); u.h[7] = f2bf(b.w);
        ((uint4*)dst)[i] = u.v;
    }
}

// ---------------------------------------------------------------------------
// GEMM  C[M][1024] = A[M][K](bf16) * B[1024][K]^T (bf16, weights are [out][in])
// MODE 0: plain fp32 write to outF
// MODE 1: QKV fused: RoPE via table on Q(z=0, scaled by 0.125*log2e for
//   exp2-domain softmax) and K(z=1) -> [bh][s][64]; V(z=2) -> [bh][64][s].
//   Epilogue staged through LDS for full-128B-line stores.
// ---------------------------------------------------------------------------
template <int MODE>
__global__ __launch_bounds__(256) void gemm_bt(
    const unsigned short* __restrict__ A,
    const unsigned short* __restrict__ B0,
    const unsigned short* __restrict__ B1,
    const unsigned short* __restrict__ B2,
    float* __restrict__ outF,
    unsigned short* __restrict__ Qh,
    unsigned short* __restrict__ Kh,
    unsigned short* __restrict__ Vt,
    const float2* __restrict__ tab,
    int M, int K)
{
    __shared__ unsigned short As[128 * 32];
    __shared__ unsigned short Bs[128 * 32];

    const int lane = threadIdx.x & 63;
    const int wid  = threadIdx.x >> 6;
    const int l15 = lane & 15, lhi = lane >> 4;
    const int m0 = blockIdx.y * 128;
    const int n0 = blockIdx.x * 128;
    const int z  = (MODE == 1) ? (int)blockIdx.z : 0;
    const unsigned short* B = (z == 0) ? B0 : (z == 1) ? B1 : B2;
    const int waveM = (wid >> 1) * 64;
    const int waveN = (wid & 1) * 64;

    f32x4 acc[4][4];
    f32x4 zero = {0.f, 0.f, 0.f, 0.f};
#pragma unroll
    for (int m = 0; m < 4; ++m)
#pragma unroll
        for (int n = 0; n < 4; ++n) acc[m][n] = zero;

    const int lrow = lane >> 2;
    const int lcol = (lane & 3) * 8;

    for (int k0 = 0; k0 < K; k0 += 32) {
#pragma unroll
        for (int q = 0; q < 2; ++q) {
            int rbase = wid * 32 + q * 16;
            const unsigned short* gA = A + (size_t)(m0 + rbase + lrow) * K + k0 + lcol;
            gload16(gA, (char*)As + rbase * 64);
            const unsigned short* gB = B + (size_t)(n0 + rbase + lrow) * K + k0 + lcol;
            gload16(gB, (char*)Bs + rbase * 64);
        }
        __syncthreads();
        bf16x8 af[4], bfr[4];
#pragma unroll
        for (int m = 0; m < 4; ++m)
            af[m] = *(const bf16x8*)(As + (waveM + m * 16 + l15) * 32 + lhi * 8);
#pragma unroll
        for (int n = 0; n < 4; ++n)
            bfr[n] = *(const bf16x8*)(Bs + (waveN + n * 16 + l15) * 32 + lhi * 8);
#pragma unroll
        for (int m = 0; m < 4; ++m)
#pragma unroll
            for (int n = 0; n < 4; ++n)
                acc[m][n] = __builtin_amdgcn_mfma_f32_16x16x32_bf16(af[m], bfr[n], acc[m][n], 0, 0, 0);
        __syncthreads();
    }

    if constexpr (MODE == 0) {
#pragma unroll
        for (int n = 0; n < 4; ++n) {
            int col = n0 + waveN + n * 16 + l15;
#pragma unroll
            for (int m = 0; m < 4; ++m) {
                int rowb = m0 + waveM + m * 16 + (lhi << 2);
#pragma unroll
                for (int r = 0; r < 4; ++r)
                    outF[(size_t)(rowb + r) * D_MODEL + col] = acc[m][n][r];
            }
        }
    } else {
        __shared__ unsigned short Ct[4][64][72];
        const int colg0 = n0 + waveN;
        const int hh    = (colg0 >> 6) & (NH - 1);
        const int rowg0 = m0 + waveM;
        const int bb    = rowg0 >> 11;
        const size_t bhh = (size_t)(bb * NH + hh);

#pragma unroll
        for (int n = 0; n < 4; ++n) {
            int cl = n * 16 + l15;
#pragma unroll
            for (int m = 0; m < 4; ++m) {
#pragma unroll
                for (int r = 0; r < 4; ++r) {
                    float v  = acc[m][n][r];
                    float pv = __shfl_xor(v, 1);
                    int rl = m * 16 + (lhi << 2) + r;
                    if (z == 2) {
                        Ct[wid][cl][rl] = f2bf(v);
                    } else {
                        int ss = (rowg0 + rl) & (SEQ - 1);
                        float2 cs = tab[(ss << 5) + (cl >> 1)];
                        float o = (cl & 1) ? (pv * cs.y + v * cs.x)
                                           : (v * cs.x - pv * cs.y);
                        if (z == 0) o *= 0.18033688011f;  // (1/8)*log2(e): exp2-domain softmax
                        Ct[wid][rl][cl] = f2bf(o);
                    }
                }
            }
        }
        asm volatile("s_waitcnt lgkmcnt(0)" ::: "memory");

        const int lr = lane >> 3;
        const int lc = (lane & 7) << 3;
#pragma unroll
        for (int i = 0; i < 8; ++i) {
            int rl = i * 8 + lr;
            uint4 w = *(const uint4*)&Ct[wid][rl][lc];
            if (z == 2) {
                int ss0 = rowg0 & (SEQ - 1);
                *(uint4*)(Vt + (bhh * DK + rl) * SEQ + ss0 + lc) = w;
            } else {
                int ss = (rowg0 + rl) & (SEQ - 1);
                unsigned short* dst = (z == 0) ? Qh : Kh;
                *(uint4*)(dst + (bhh * SEQ + ss) * DK + lc) = w;
            }
        }
    }
}

// ---------------------------------------------------------------------------
// causal flash attention v4:
//  - block = 4 waves, handles TWO 64-row q-tiles (i, 31-i) sequentially ->
//    uniform work per block (fixes triangular drain; R4 occupancy 22%)
//  - K/V tiles (128 kv x 64 d) staged in LDS once per block, shared by all
//    4 waves (fixes 4x-redundant L3 round-trips; KV set 16MB >> L2 4MB)
//  - reg-staged prefetch: loads for tile t+1 issued after the post-write
//    barrier, drained at next iteration's barrier -> full compute to fly
//  - P buffer: XOR (chunk^row) swizzle, 8-way -> ~4-way read conflicts
// Qh/Kh: [bh][s][64] bf16 (Q pre-scaled 0.125*log2e); Vt: [bh][64][s] bf16.
// ---------------------------------------------------------------------------
__global__ __launch_bounds__(256) void attn_kernel(
    const unsigned short* __restrict__ Qh,
    const unsigned short* __restrict__ Kh,
    const unsigned short* __restrict__ Vt,
    unsigned short* __restrict__ O)
{
    __shared__ unsigned short Ks[128][72];   // kv-row major, +8 pad: 2-way reads
    __shared__ unsigned short Vs[64][136];   // d-row major,  +8 pad: 2-way reads
    __shared__ unsigned short P[4][16][128]; // XOR-swizzled, per-wave

    const int tid  = threadIdx.x;
    const int lane = tid & 63;
    const int wid  = tid >> 6;
    const int l15 = lane & 15, lhi = lane >> 4;
    const int bh = blockIdx.x;
    const int pi = blockIdx.y;          // pair index 0..15
    const int b = bh >> 4, h = bh & 15;

    const unsigned short* Qb = Qh + (size_t)bh * SEQ * DK;
    const unsigned short* Kb = Kh + (size_t)bh * SEQ * DK;
    const unsigned short* Vb = Vt + (size_t)bh * DK * SEQ;

    uint4 rK[4], rV[4];
    auto STAGE = [&](int kv0s) {
#pragma unroll
        for (int c = 0; c < 4; ++c)
            rK[c] = *(const uint4*)(Kb + (size_t)kv0s * DK + c * 2048 + tid * 8);
#pragma unroll
        for (int c = 0; c < 4; ++c)
            rV[c] = *(const uint4*)(Vb + (size_t)(c * 16 + (tid >> 4)) * SEQ + kv0s + ((tid & 15) << 3));
    };
    auto WRITE_STAGED = [&]() {
#pragma unroll
        for (int c = 0; c < 4; ++c) {
            int e = c * 2048 + tid * 8;
            *(uint4*)&Ks[e >> 6][e & 63] = rK[c];
        }
#pragma unroll
        for (int c = 0; c < 4; ++c)
            *(uint4*)&Vs[c * 16 + (tid >> 4)][(tid & 15) << 3] = rV[c];
    };

    const f32x4 zero = {0.f, 0.f, 0.f, 0.f};
    const f32x4 ninf = {-1e30f, -1e30f, -1e30f, -1e30f};

    STAGE(0);

    for (int ph = 0; ph < 2; ++ph) {
        const int qt = ph ? (31 - pi) : pi;
        const int ktl = qt >> 1;            // last 128-wide kv tile
        const int q0 = qt * 64;
        const int qw = q0 + wid * 16;

        bf16x8 qf[2];
#pragma unroll
        for (int kk = 0; kk < 2; ++kk)
            qf[kk] = *(const bf16x8*)(Qb + (size_t)(qw + l15) * DK + kk * 32 + lhi * 8);

        f32x4 oacc[4];
#pragma unroll
        for (int nd = 0; nd < 4; ++nd) oacc[nd] = zero;
        float mrow = -1e30f;
        float lrow = 0.f;

        for (int kt = 0; kt <= ktl; ++kt) {
            const int kv0 = kt << 7;
            const bool diag = (kt == ktl);
            const int nlim = diag ? (((qw - kv0) >> 4) + 1) : 8;

            __syncthreads();               // prev compute done; prefetch drained
            WRITE_STAGED();
            __syncthreads();               // staged tile visible
            const bool hasNext = (kt < ktl) || (ph == 0);
            if (hasNext) STAGE(kt < ktl ? (kt + 1) << 7 : 0);  // flies during compute

            f32x4 s[8];  // s[n][r]: k = kv0+n*16+(lhi<<2)+r, q = qw+l15
#pragma unroll
            for (int n = 0; n < 8; ++n) s[n] = (n < nlim) ? zero : ninf;

            __builtin_amdgcn_s_setprio(1);
#pragma unroll
            for (int n = 0; n < 8; ++n) {
                if (n < nlim) {
                    bf16x8 k0 = *(const bf16x8*)&Ks[n * 16 + l15][lhi * 8];
                    bf16x8 k1 = *(const bf16x8*)&Ks[n * 16 + l15][32 + lhi * 8];
                    s[n] = __builtin_amdgcn_mfma_f32_16x16x32_bf16(k0, qf[0], s[n], 0, 0, 0);
                    s[n] = __builtin_amdgcn_mfma_f32_16x16x32_bf16(k1, qf[1], s[n], 0, 0, 0);
                }
            }
            __builtin_amdgcn_s_setprio(0);

            if (diag) {  // causal: mask k > q
                const int qg = qw + l15;
#pragma unroll
                for (int n = 0; n < 8; ++n) {
                    if (n < nlim) {
#pragma unroll
                        for (int r = 0; r < 4; ++r) {
                            int kg = kv0 + n * 16 + (lhi << 2) + r;
                            if (kg > qg) s[n][r] = -1e30f;
                        }
                    }
                }
            }

            // row max: local tree + 2 shfls
            float mx = fmaxf(fmaxf(s[0][0], s[0][1]), fmaxf(s[0][2], s[0][3]));
#pragma unroll
            for (int n = 1; n < 8; ++n)
                mx = fmaxf(mx, fmaxf(fmaxf(s[n][0], s[n][1]), fmaxf(s[n][2], s[n][3])));
            mx = fmaxf(mx, __shfl_xor(mx, 16));
            mx = fmaxf(mx, __shfl_xor(mx, 32));

            float alpha = 1.f;
            const int allDefer = __all(mx <= mrow + 8.f);
            if (!allDefer) {
                float mn = fmaxf(mrow, mx);
                alpha = __builtin_amdgcn_exp2f(mrow - mn);
                mrow = mn;
            }

#pragma unroll
            for (int n = 0; n < 8; ++n)
#pragma unroll
                for (int r = 0; r < 4; ++r)
                    s[n][r] = __builtin_amdgcn_exp2f(s[n][r] - mrow);

            float rs = 0.f;
#pragma unroll
            for (int n = 0; n < 8; ++n)
                rs += (s[n][0] + s[n][1]) + (s[n][2] + s[n][3]);
            rs += __shfl_xor(rs, 16);
            rs += __shfl_xor(rs, 32);
            lrow = allDefer ? (lrow + rs) : (lrow * alpha + rs);

            // P -> LDS, XOR-swizzled (chunk ^ row), uint2 per n
#pragma unroll
            for (int n = 0; n < 8; ++n) {
                union { unsigned short hh4[4]; uint2 v; } pk;
#pragma unroll
                for (int r = 0; r < 4; ++r) pk.hh4[r] = f2bf(s[n][r]);
                int cW = 2 * n + (lhi >> 1);
                *(uint2*)&P[wid][l15][((cW ^ l15) << 3) + ((lhi & 1) << 2)] = pk.v;
            }

            if (!allDefer) {
                float a0 = __shfl(alpha, (lhi << 2) + 0);
                float a1 = __shfl(alpha, (lhi << 2) + 1);
                float a2 = __shfl(alpha, (lhi << 2) + 2);
                float a3 = __shfl(alpha, (lhi << 2) + 3);
#pragma unroll
                for (int nd = 0; nd < 4; ++nd) {
                    oacc[nd][0] *= a0; oacc[nd][1] *= a1;
                    oacc[nd][2] *= a2; oacc[nd][3] *= a3;
                }
            }

            asm volatile("s_waitcnt lgkmcnt(0)" ::: "memory");
            const int kklim = diag ? ((nlim + 1) >> 1) : 4;
            bf16x8 pa[4];
#pragma unroll
            for (int kk = 0; kk < 4; ++kk)
                if (kk < kklim)
                    pa[kk] = *(const bf16x8*)&P[wid][l15][((4 * kk + lhi) ^ l15) << 3];

            __builtin_amdgcn_s_setprio(1);
#pragma unroll
            for (int nd = 0; nd < 4; ++nd)
#pragma unroll
                for (int kk = 0; kk < 4; ++kk)
                    if (kk < kklim) {
                        bf16x8 vf = *(const bf16x8*)&Vs[nd * 16 + l15][kk * 32 + lhi * 8];
                        oacc[nd] = __builtin_amdgcn_mfma_f32_16x16x32_bf16(pa[kk], vf, oacc[nd], 0, 0, 0);
                    }
            __builtin_amdgcn_s_setprio(0);
        }

        float inv = 1.f / lrow;
        float i0 = __shfl(inv, (lhi << 2) + 0);
        float i1 = __shfl(inv, (lhi << 2) + 1);
        float i2 = __shfl(inv, (lhi << 2) + 2);
        float i3 = __shfl(inv, (lhi << 2) + 3);
#pragma unroll
        for (int nd = 0; nd < 4; ++nd) {
            int d = nd * 16 + l15;
            int rowb = qw + (lhi << 2);
            O[((size_t)(b * SEQ + rowb + 0)) * D_MODEL + h * DK + d] = f2bf(oacc[nd][0] * i0);
            O[((size_t)(b * SEQ + rowb + 1)) * D_MODEL + h * DK + d] = f2bf(oacc[nd][1] * i1);
            O[((size_t)(b * SEQ + rowb + 2)) * D_MODEL + h * DK + d] = f2bf(oacc[nd][2] * i2);
            O[((size_t)(b * SEQ + rowb + 3)) * D_MODEL + h * DK + d] = f2bf(oacc[nd][3] * i3);
        }
    }
}

// ---------------------------------------------------------------------------
extern "C" void kernel_launch(void* const* d_in, const int* in_sizes, int n_in,
                              void* d_out, int out_size, void* d_ws, size_t ws_size,
                              hipStream_t stream)
{
    const float* x  = (const float*)d_in[0];
    const float* Wq = (const float*)d_in[1];
    const float* Wk = (const float*)d_in[2];
    const float* Wv = (const float*)d_in[3];
    const float* Wo = (const float*)d_in[4];
    float* out = (float*)d_out;

    char* ws = (char*)d_ws;
    unsigned short* xb  = (unsigned short*)(ws);                    // 8 MB (reused as attn buf)
    unsigned short* Wqb = (unsigned short*)(ws + ( 8ull << 20));
    unsigned short* Wkb = (unsigned short*)(ws + (10ull << 20));
    unsigned short* Wvb = (unsigned short*)(ws + (12ull << 20));
    unsigned short* Wob = (unsigned short*)(ws + (14ull << 20));
    unsigned short* Qh  = (unsigned short*)(ws + (16ull << 20));    // [bh][s][64]
    unsigned short* Kh  = (unsigned short*)(ws + (24ull << 20));    // [bh][s][64]
    unsigned short* Vt  = (unsigned short*)(ws + (32ull << 20));    // [bh][64][s]
    float2*         tab = (float2*)(ws + (40ull << 20));            // 512 KB RoPE table
    unsigned short* attn = xb;

    cast5<<<dim3(512, 6), 256, 0, stream>>>(x, Wq, Wk, Wv, Wo, xb, Wqb, Wkb, Wvb, Wob, tab);

    gemm_bt<1><<<dim3(D_MODEL / 128, (NB * SEQ) / 128, 3), 256, 0, stream>>>(
        xb, Wqb, Wkb, Wvb, nullptr, Qh, Kh, Vt, tab, NB * SEQ, D_MODEL);

    attn_kernel<<<dim3(NB * NH, 16), 256, 0, stream>>>(Qh, Kh, Vt, attn);

    gemm_bt<0><<<dim3(D_MODEL / 128, (NB * SEQ) / 128, 1), 256, 0, stream>>>(
        attn, Wob, Wob, Wob, out, nullptr, nullptr, nullptr, nullptr, NB * SEQ, D_MODEL);
}

// Round 6
// 145.977 us; speedup vs baseline: 1.4095x; 1.2559x over previous
//
#include <hip/hip_runtime.h>

typedef float f32x4 __attribute__((ext_vector_type(4)));
typedef __bf16 bf16x8 __attribute__((ext_vector_type(8)));

#define D_MODEL 1024
#define SEQ     2048
#define NB      2
#define NH      16
#define DK      64

__device__ __forceinline__ unsigned short f2bf(float f) {
    union { float f; unsigned int u; } un; un.f = f;
    unsigned int r = un.u + 0x7fffu + ((un.u >> 16) & 1u);
    return (unsigned short)(r >> 16);
}

__device__ __forceinline__ void gload16(const void* g, void* l) {
    __builtin_amdgcn_global_load_lds((__attribute__((address_space(1))) void*)g,
                                     (__attribute__((address_space(3))) void*)l,
                                     16, 0, 0);
}

// ---------------------------------------------------------------------------
// fused fp32 -> bf16 casts for x and the 4 weights + RoPE cos/sin table
// ---------------------------------------------------------------------------
__global__ __launch_bounds__(256) void cast5(
    const float* __restrict__ x,  const float* __restrict__ wq,
    const float* __restrict__ wk, const float* __restrict__ wv,
    const float* __restrict__ wo,
    unsigned short* __restrict__ xb,  unsigned short* __restrict__ wqb,
    unsigned short* __restrict__ wkb, unsigned short* __restrict__ wvb,
    unsigned short* __restrict__ wob, float2* __restrict__ tab)
{
    if (blockIdx.y == 5) {  // RoPE table: [ss][p] -> (cos, sin), p = d/2 index
        int idx = blockIdx.x * 256 + threadIdx.x;
        if (idx < SEQ * 32) {
            int ss = idx >> 5, p = idx & 31;
            float freq = exp2f(-0.41524101186f * (float)p);  // 10000^(-p/32)
            float sn, cs;
            sincosf((float)ss * freq, &sn, &cs);
            tab[idx] = make_float2(cs, sn);
        }
        return;
    }
    const float* src; unsigned short* dst; int n8;
    switch (blockIdx.y) {
        case 0:  src = x;  dst = xb;  n8 = (NB*SEQ*D_MODEL)/8; break;
        case 1:  src = wq; dst = wqb; n8 = (D_MODEL*D_MODEL)/8; break;
        case 2:  src = wk; dst = wkb; n8 = (D_MODEL*D_MODEL)/8; break;
        case 3:  src = wv; dst = wvb; n8 = (D_MODEL*D_MODEL)/8; break;
        default: src = wo; dst = wob; n8 = (D_MODEL*D_MODEL)/8; break;
    }
    int stride = gridDim.x * blockDim.x;
    for (int i = blockIdx.x * blockDim.x + threadIdx.x; i < n8; i += stride) {
        const float4* p = (const float4*)src + (size_t)i * 2;
        float4 a = p[0], b = p[1];
        union { unsigned short h[8]; uint4 v; } u;
        u.h[0] = f2bf(a.x); u.h[1] = f2bf(a.y); u.h[2] = f2bf(a.z); u.h[3] = f2bf(a.w);
        u.h[4] = f2bf(b.x); u.h[5] = f2bf(b.y); u.h[6] = f2bf(b.z); u.h[7] = f2bf(b.w);
        ((uint4*)dst)[i] = u.v;
    }
}

// ---------------------------------------------------------------------------
// GEMM  C[M][1024] = A[M][K](bf16) * B[1024][K]^T (bf16, weights are [out][in])
// MODE 0: plain fp32 write to outF
// MODE 1: QKV fused: RoPE via table on Q(z=0, scaled by 0.125*log2e for
//   exp2-domain softmax) and K(z=1) -> [bh][s][64]; V(z=2) -> [bh][64][s].
//   Epilogue staged through LDS for full-128B-line stores.
// ---------------------------------------------------------------------------
template <int MODE>
__global__ __launch_bounds__(256) void gemm_bt(
    const unsigned short* __restrict__ A,
    const unsigned short* __restrict__ B0,
    const unsigned short* __restrict__ B1,
    const unsigned short* __restrict__ B2,
    float* __restrict__ outF,
    unsigned short* __restrict__ Qh,
    unsigned short* __restrict__ Kh,
    unsigned short* __restrict__ Vt,
    const float2* __restrict__ tab,
    int M, int K)
{
    __shared__ unsigned short As[128 * 32];
    __shared__ unsigned short Bs[128 * 32];

    const int lane = threadIdx.x & 63;
    const int wid  = threadIdx.x >> 6;
    const int l15 = lane & 15, lhi = lane >> 4;
    const int m0 = blockIdx.y * 128;
    const int n0 = blockIdx.x * 128;
    const int z  = (MODE == 1) ? (int)blockIdx.z : 0;
    const unsigned short* B = (z == 0) ? B0 : (z == 1) ? B1 : B2;
    const int waveM = (wid >> 1) * 64;
    const int waveN = (wid & 1) * 64;

    f32x4 acc[4][4];
    f32x4 zero = {0.f, 0.f, 0.f, 0.f};
#pragma unroll
    for (int m = 0; m < 4; ++m)
#pragma unroll
        for (int n = 0; n < 4; ++n) acc[m][n] = zero;

    const int lrow = lane >> 2;
    const int lcol = (lane & 3) * 8;

    for (int k0 = 0; k0 < K; k0 += 32) {
#pragma unroll
        for (int q = 0; q < 2; ++q) {
            int rbase = wid * 32 + q * 16;
            const unsigned short* gA = A + (size_t)(m0 + rbase + lrow) * K + k0 + lcol;
            gload16(gA, (char*)As + rbase * 64);
            const unsigned short* gB = B + (size_t)(n0 + rbase + lrow) * K + k0 + lcol;
            gload16(gB, (char*)Bs + rbase * 64);
        }
        __syncthreads();
        bf16x8 af[4], bfr[4];
#pragma unroll
        for (int m = 0; m < 4; ++m)
            af[m] = *(const bf16x8*)(As + (waveM + m * 16 + l15) * 32 + lhi * 8);
#pragma unroll
        for (int n = 0; n < 4; ++n)
            bfr[n] = *(const bf16x8*)(Bs + (waveN + n * 16 + l15) * 32 + lhi * 8);
#pragma unroll
        for (int m = 0; m < 4; ++m)
#pragma unroll
            for (int n = 0; n < 4; ++n)
                acc[m][n] = __builtin_amdgcn_mfma_f32_16x16x32_bf16(af[m], bfr[n], acc[m][n], 0, 0, 0);
        __syncthreads();
    }

    if constexpr (MODE == 0) {
#pragma unroll
        for (int n = 0; n < 4; ++n) {
            int col = n0 + waveN + n * 16 + l15;
#pragma unroll
            for (int m = 0; m < 4; ++m) {
                int rowb = m0 + waveM + m * 16 + (lhi << 2);
#pragma unroll
                for (int r = 0; r < 4; ++r)
                    outF[(size_t)(rowb + r) * D_MODEL + col] = acc[m][n][r];
            }
        }
    } else {
        __shared__ unsigned short Ct[4][64][72];
        const int colg0 = n0 + waveN;
        const int hh    = (colg0 >> 6) & (NH - 1);
        const int rowg0 = m0 + waveM;
        const int bb    = rowg0 >> 11;
        const size_t bhh = (size_t)(bb * NH + hh);

#pragma unroll
        for (int n = 0; n < 4; ++n) {
            int cl = n * 16 + l15;
#pragma unroll
            for (int m = 0; m < 4; ++m) {
#pragma unroll
                for (int r = 0; r < 4; ++r) {
                    float v  = acc[m][n][r];
                    float pv = __shfl_xor(v, 1);
                    int rl = m * 16 + (lhi << 2) + r;
                    if (z == 2) {
                        Ct[wid][cl][rl] = f2bf(v);
                    } else {
                        int ss = (rowg0 + rl) & (SEQ - 1);
                        float2 cs = tab[(ss << 5) + (cl >> 1)];
                        float o = (cl & 1) ? (pv * cs.y + v * cs.x)
                                           : (v * cs.x - pv * cs.y);
                        if (z == 0) o *= 0.18033688011f;  // (1/8)*log2(e): exp2-domain softmax
                        Ct[wid][rl][cl] = f2bf(o);
                    }
                }
            }
        }
        asm volatile("s_waitcnt lgkmcnt(0)" ::: "memory");

        const int lr = lane >> 3;
        const int lc = (lane & 7) << 3;
#pragma unroll
        for (int i = 0; i < 8; ++i) {
            int rl = i * 8 + lr;
            uint4 w = *(const uint4*)&Ct[wid][rl][lc];
            if (z == 2) {
                int ss0 = rowg0 & (SEQ - 1);
                *(uint4*)(Vt + (bhh * DK + rl) * SEQ + ss0 + lc) = w;
            } else {
                int ss = (rowg0 + rl) & (SEQ - 1);
                unsigned short* dst = (z == 0) ? Qh : Kh;
                *(uint4*)(dst + (bhh * SEQ + ss) * DK + lc) = w;
            }
        }
    }
}

// ---------------------------------------------------------------------------
// causal flash attention v5:
//  - block = 4 waves, TWO paired q-tiles (pi, 31-pi) -> uniform work
//  - K/V double-buffered in LDS via global_load_lds (NO reg staging: R5's
//    rK/rV spilled to scratch -> 231 MB HBM writes). Prefetch of tile t+1
//    issued right after the barrier, flies across tile t's full compute.
//  - T2 both-sides swizzle: linear LDS dest (gload_lds requirement), global
//    source pre-swizzled (colu ^= row&7), ds_read applies same XOR -> 2-way.
//  - one vmcnt(0)+barrier per kv-iteration.
// Qh/Kh: [bh][s][64] bf16 (Q pre-scaled 0.125*log2e); Vt: [bh][64][s] bf16.
// ---------------------------------------------------------------------------
__global__ __launch_bounds__(256) void attn_kernel(
    const unsigned short* __restrict__ Qh,
    const unsigned short* __restrict__ Kh,
    const unsigned short* __restrict__ Vt,
    unsigned short* __restrict__ O)
{
    __shared__ unsigned short Ks[2][128 * 64];   // 16 KB x2, row-major, swizzled units
    __shared__ unsigned short Vs[2][64 * 128];   // 16 KB x2, d-major,   swizzled units
    __shared__ unsigned short P[4][16 * 128];    // per-wave P, XOR-swizzled

    const int tid  = threadIdx.x;
    const int lane = tid & 63;
    const int wid  = tid >> 6;
    const int l15 = lane & 15, lhi = lane >> 4;
    const int bh = blockIdx.x;
    const int pi = blockIdx.y;          // pair index 0..15
    const int b = bh >> 4, h = bh & 15;

    const unsigned short* Qb = Qh + (size_t)bh * SEQ * DK;
    const unsigned short* Kb = Kh + (size_t)bh * SEQ * DK;
    const unsigned short* Vb = Vt + (size_t)bh * DK * SEQ;

    // stage one 128-kv tile: K (128 rows x 64d) + V (64 d-rows x 128 kv)
    // 16B units; LDS linear in unit order, global source inverse-swizzled.
    auto STAGE = [&](int buf, int kv0s) {
#pragma unroll
        for (int c = 0; c < 4; ++c) {
            int ub = wid * 256 + c * 64;   // wave-uniform unit base
            int u  = ub + lane;
            int kr = u >> 3;               // K row (0..127)
            int kc = (u & 7) ^ (kr & 7);   // inverse-swizzled col unit
            gload16(Kb + (size_t)(kv0s + kr) * DK + kc * 8, &Ks[buf][ub * 8]);
            int vr = u >> 4;               // V d-row (0..63)
            int vc = (u & 15) ^ (vr & 7);
            gload16(Vb + (size_t)vr * SEQ + kv0s + vc * 8, &Vs[buf][ub * 8]);
        }
    };

    const f32x4 zero = {0.f, 0.f, 0.f, 0.f};
    const f32x4 ninf = {-1e30f, -1e30f, -1e30f, -1e30f};

    STAGE(0, 0);
    int cur = 0;

    for (int ph = 0; ph < 2; ++ph) {
        const int qt = ph ? (31 - pi) : pi;
        const int ktl = qt >> 1;            // last 128-wide kv tile
        const int q0 = qt * 64;
        const int qw = q0 + wid * 16;

        bf16x8 qf[2];
#pragma unroll
        for (int kk = 0; kk < 2; ++kk)
            qf[kk] = *(const bf16x8*)(Qb + (size_t)(qw + l15) * DK + kk * 32 + lhi * 8);

        f32x4 oacc[4];
#pragma unroll
        for (int nd = 0; nd < 4; ++nd) oacc[nd] = zero;
        float mrow = -1e30f;
        float lrow = 0.f;

        for (int kt = 0; kt <= ktl; ++kt) {
            const int kv0 = kt << 7;
            const bool diag = (kt == ktl);
            const int nlim = diag ? (((qw - kv0) >> 4) + 1) : 8;

            // current tile's loads (issued last iter / prologue) are the only
            // outstanding VMEM -> drain own, then join all waves.
            asm volatile("s_waitcnt vmcnt(0)" ::: "memory");
            __builtin_amdgcn_s_barrier();
            __builtin_amdgcn_sched_barrier(0);

            // prefetch next tile into the buffer everyone just finished with
            const bool hasNext = (kt < ktl) || (ph == 0);
            if (hasNext) STAGE(cur ^ 1, (kt < ktl) ? (kv0 + 128) : 0);

            f32x4 s[8];  // s[n][r]: k = kv0+n*16+(lhi<<2)+r, q = qw+l15
#pragma unroll
            for (int n = 0; n < 8; ++n) s[n] = (n < nlim) ? zero : ninf;

            const int sw = l15 & 7;
            __builtin_amdgcn_s_setprio(1);
#pragma unroll
            for (int n = 0; n < 8; ++n) {
                if (n < nlim) {
                    int r = n * 16 + l15;
                    bf16x8 k0 = *(const bf16x8*)&Ks[cur][r * 64 + ((lhi ^ sw) << 3)];
                    bf16x8 k1 = *(const bf16x8*)&Ks[cur][r * 64 + (((4 + lhi) ^ sw) << 3)];
                    s[n] = __builtin_amdgcn_mfma_f32_16x16x32_bf16(k0, qf[0], s[n], 0, 0, 0);
                    s[n] = __builtin_amdgcn_mfma_f32_16x16x32_bf16(k1, qf[1], s[n], 0, 0, 0);
                }
            }
            __builtin_amdgcn_s_setprio(0);

            if (diag) {  // causal: mask k > q
                const int qg = qw + l15;
#pragma unroll
                for (int n = 0; n < 8; ++n) {
                    if (n < nlim) {
#pragma unroll
                        for (int r = 0; r < 4; ++r) {
                            int kg = kv0 + n * 16 + (lhi << 2) + r;
                            if (kg > qg) s[n][r] = -1e30f;
                        }
                    }
                }
            }

            // row max: local tree + 2 shfls
            float mx = fmaxf(fmaxf(s[0][0], s[0][1]), fmaxf(s[0][2], s[0][3]));
#pragma unroll
            for (int n = 1; n < 8; ++n)
                mx = fmaxf(mx, fmaxf(fmaxf(s[n][0], s[n][1]), fmaxf(s[n][2], s[n][3])));
            mx = fmaxf(mx, __shfl_xor(mx, 16));
            mx = fmaxf(mx, __shfl_xor(mx, 32));

            float alpha = 1.f;
            const int allDefer = __all(mx <= mrow + 8.f);
            if (!allDefer) {
                float mn = fmaxf(mrow, mx);
                alpha = __builtin_amdgcn_exp2f(mrow - mn);
                mrow = mn;
            }

#pragma unroll
            for (int n = 0; n < 8; ++n)
#pragma unroll
                for (int r = 0; r < 4; ++r)
                    s[n][r] = __builtin_amdgcn_exp2f(s[n][r] - mrow);

            float rs = 0.f;
#pragma unroll
            for (int n = 0; n < 8; ++n)
                rs += (s[n][0] + s[n][1]) + (s[n][2] + s[n][3]);
            rs += __shfl_xor(rs, 16);
            rs += __shfl_xor(rs, 32);
            lrow = allDefer ? (lrow + rs) : (lrow * alpha + rs);

            // P -> LDS, XOR-swizzled (chunk ^ row), uint2 per n
#pragma unroll
            for (int n = 0; n < 8; ++n) {
                union { unsigned short hh4[4]; uint2 v; } pk;
#pragma unroll
                for (int r = 0; r < 4; ++r) pk.hh4[r] = f2bf(s[n][r]);
                int cW = 2 * n + (lhi >> 1);
                *(uint2*)&P[wid][(l15 << 7) + (((cW ^ l15) << 3) + ((lhi & 1) << 2))] = pk.v;
            }

            if (!allDefer) {
                float a0 = __shfl(alpha, (lhi << 2) + 0);
                float a1 = __shfl(alpha, (lhi << 2) + 1);
                float a2 = __shfl(alpha, (lhi << 2) + 2);
                float a3 = __shfl(alpha, (lhi << 2) + 3);
#pragma unroll
                for (int nd = 0; nd < 4; ++nd) {
                    oacc[nd][0] *= a0; oacc[nd][1] *= a1;
                    oacc[nd][2] *= a2; oacc[nd][3] *= a3;
                }
            }

            asm volatile("s_waitcnt lgkmcnt(0)" ::: "memory");
            const int kklim = diag ? ((nlim + 1) >> 1) : 4;
            bf16x8 pa[4];
#pragma unroll
            for (int kk = 0; kk < 4; ++kk)
                if (kk < kklim)
                    pa[kk] = *(const bf16x8*)&P[wid][(l15 << 7) + ((((kk << 2) + lhi) ^ l15) << 3)];

            __builtin_amdgcn_s_setprio(1);
#pragma unroll
            for (int nd = 0; nd < 4; ++nd)
#pragma unroll
                for (int kk = 0; kk < 4; ++kk)
                    if (kk < kklim) {
                        int rd = nd * 16 + l15;
                        bf16x8 vf = *(const bf16x8*)&Vs[cur][rd * 128 + ((((kk << 2) + lhi) ^ sw) << 3)];
                        oacc[nd] = __builtin_amdgcn_mfma_f32_16x16x32_bf16(pa[kk], vf, oacc[nd], 0, 0, 0);
                    }
            __builtin_amdgcn_s_setprio(0);

            cur ^= 1;
        }

        float inv = 1.f / lrow;
        float i0 = __shfl(inv, (lhi << 2) + 0);
        float i1 = __shfl(inv, (lhi << 2) + 1);
        float i2 = __shfl(inv, (lhi << 2) + 2);
        float i3 = __shfl(inv, (lhi << 2) + 3);
#pragma unroll
        for (int nd = 0; nd < 4; ++nd) {
            int d = nd * 16 + l15;
            int rowb = qw + (lhi << 2);
            O[((size_t)(b * SEQ + rowb + 0)) * D_MODEL + h * DK + d] = f2bf(oacc[nd][0] * i0);
            O[((size_t)(b * SEQ + rowb + 1)) * D_MODEL + h * DK + d] = f2bf(oacc[nd][1] * i1);
            O[((size_t)(b * SEQ + rowb + 2)) * D_MODEL + h * DK + d] = f2bf(oacc[nd][2] * i2);
            O[((size_t)(b * SEQ + rowb + 3)) * D_MODEL + h * DK + d] = f2bf(oacc[nd][3] * i3);
        }
    }
}

// ---------------------------------------------------------------------------
extern "C" void kernel_launch(void* const* d_in, const int* in_sizes, int n_in,
                              void* d_out, int out_size, void* d_ws, size_t ws_size,
                              hipStream_t stream)
{
    const float* x  = (const float*)d_in[0];
    const float* Wq = (const float*)d_in[1];
    const float* Wk = (const float*)d_in[2];
    const float* Wv = (const float*)d_in[3];
    const float* Wo = (const float*)d_in[4];
    float* out = (float*)d_out;

    char* ws = (char*)d_ws;
    unsigned short* xb  = (unsigned short*)(ws);                    // 8 MB (reused as attn buf)
    unsigned short* Wqb = (unsigned short*)(ws + ( 8ull << 20));
    unsigned short* Wkb = (unsigned short*)(ws + (10ull << 20));
    unsigned short* Wvb = (unsigned short*)(ws + (12ull << 20));
    unsigned short* Wob = (unsigned short*)(ws + (14ull << 20));
    unsigned short* Qh  = (unsigned short*)(ws + (16ull << 20));    // [bh][s][64]
    unsigned short* Kh  = (unsigned short*)(ws + (24ull << 20));    // [bh][s][64]
    unsigned short* Vt  = (unsigned short*)(ws + (32ull << 20));    // [bh][64][s]
    float2*         tab = (float2*)(ws + (40ull << 20));            // 512 KB RoPE table
    unsigned short* attn = xb;

    cast5<<<dim3(512, 6), 256, 0, stream>>>(x, Wq, Wk, Wv, Wo, xb, Wqb, Wkb, Wvb, Wob, tab);

    gemm_bt<1><<<dim3(D_MODEL / 128, (NB * SEQ) / 128, 3), 256, 0, stream>>>(
        xb, Wqb, Wkb, Wvb, nullptr, Qh, Kh, Vt, tab, NB * SEQ, D_MODEL);

    attn_kernel<<<dim3(NB * NH, 16), 256, 0, stream>>>(Qh, Kh, Vt, attn);

    gemm_bt<0><<<dim3(D_MODEL / 128, (NB * SEQ) / 128, 1), 256, 0, stream>>>(
        attn, Wob, Wob, Wob, out, nullptr, nullptr, nullptr, nullptr, NB * SEQ, D_MODEL);
}

// Round 7
// 130.486 us; speedup vs baseline: 1.5769x; 1.1187x over previous
//
#include <hip/hip_runtime.h>

typedef float f32x4 __attribute__((ext_vector_type(4)));
typedef __bf16 bf16x8 __attribute__((ext_vector_type(8)));

#define D_MODEL 1024
#define SEQ     2048
#define NB      2
#define NH      16
#define DK      64

__device__ __forceinline__ unsigned short f2bf(float f) {
    union { float f; unsigned int u; } un; un.f = f;
    unsigned int r = un.u + 0x7fffu + ((un.u >> 16) & 1u);
    return (unsigned short)(r >> 16);
}

__device__ __forceinline__ unsigned cvtpk(float lo, float hi) {
    unsigned r;
    asm("v_cvt_pk_bf16_f32 %0, %1, %2" : "=v"(r) : "v"(lo), "v"(hi));
    return r;
}

__device__ __forceinline__ void gload16(const void* g, void* l) {
    __builtin_amdgcn_global_load_lds((__attribute__((address_space(1))) void*)g,
                                     (__attribute__((address_space(3))) void*)l,
                                     16, 0, 0);
}

// ---------------------------------------------------------------------------
// fused fp32 -> bf16 casts for x and the 4 weights + RoPE cos/sin table
// ---------------------------------------------------------------------------
__global__ __launch_bounds__(256) void cast5(
    const float* __restrict__ x,  const float* __restrict__ wq,
    const float* __restrict__ wk, const float* __restrict__ wv,
    const float* __restrict__ wo,
    unsigned short* __restrict__ xb,  unsigned short* __restrict__ wqb,
    unsigned short* __restrict__ wkb, unsigned short* __restrict__ wvb,
    unsigned short* __restrict__ wob, float2* __restrict__ tab)
{
    if (blockIdx.y == 5) {  // RoPE table: [ss][p] -> (cos, sin), p = d/2 index
        int idx = blockIdx.x * 256 + threadIdx.x;
        if (idx < SEQ * 32) {
            int ss = idx >> 5, p = idx & 31;
            float freq = exp2f(-0.41524101186f * (float)p);  // 10000^(-p/32)
            float sn, cs;
            sincosf((float)ss * freq, &sn, &cs);
            tab[idx] = make_float2(cs, sn);
        }
        return;
    }
    const float* src; unsigned short* dst; int n8;
    switch (blockIdx.y) {
        case 0:  src = x;  dst = xb;  n8 = (NB*SEQ*D_MODEL)/8; break;
        case 1:  src = wq; dst = wqb; n8 = (D_MODEL*D_MODEL)/8; break;
        case 2:  src = wk; dst = wkb; n8 = (D_MODEL*D_MODEL)/8; break;
        case 3:  src = wv; dst = wvb; n8 = (D_MODEL*D_MODEL)/8; break;
        default: src = wo; dst = wob; n8 = (D_MODEL*D_MODEL)/8; break;
    }
    int stride = gridDim.x * blockDim.x;
    for (int i = blockIdx.x * blockDim.x + threadIdx.x; i < n8; i += stride) {
        const float4* p = (const float4*)src + (size_t)i * 2;
        float4 a = p[0], b = p[1];
        union { unsigned short h[8]; uint4 v; } u;
        u.h[0] = f2bf(a.x); u.h[1] = f2bf(a.y); u.h[2] = f2bf(a.z); u.h[3] = f2bf(a.w);
        u.h[4] = f2bf(b.x); u.h[5] = f2bf(b.y); u.h[6] = f2bf(b.z); u.h[7] = f2bf(b.w);
        ((uint4*)dst)[i] = u.v;
    }
}

// ---------------------------------------------------------------------------
// GEMM  C[M][1024] = A[M][K](bf16) * B[1024][K]^T (bf16, weights are [out][in])
// MODE 0: plain fp32 write to outF
// MODE 1: QKV fused: RoPE via table on Q(z=0, scaled by 0.125*log2e for
//   exp2-domain softmax) and K(z=1) -> [bh][s][64]; V(z=2) -> [bh][64][s].
//   Epilogue staged through LDS for full-128B-line stores.
// ---------------------------------------------------------------------------
template <int MODE>
__global__ __launch_bounds__(256) void gemm_bt(
    const unsigned short* __restrict__ A,
    const unsigned short* __restrict__ B0,
    const unsigned short* __restrict__ B1,
    const unsigned short* __restrict__ B2,
    float* __restrict__ outF,
    unsigned short* __restrict__ Qh,
    unsigned short* __restrict__ Kh,
    unsigned short* __restrict__ Vt,
    const float2* __restrict__ tab,
    int M, int K)
{
    __shared__ unsigned short As[128 * 32];
    __shared__ unsigned short Bs[128 * 32];

    const int lane = threadIdx.x & 63;
    const int wid  = threadIdx.x >> 6;
    const int l15 = lane & 15, lhi = lane >> 4;
    const int m0 = blockIdx.y * 128;
    const int n0 = blockIdx.x * 128;
    const int z  = (MODE == 1) ? (int)blockIdx.z : 0;
    const unsigned short* B = (z == 0) ? B0 : (z == 1) ? B1 : B2;
    const int waveM = (wid >> 1) * 64;
    const int waveN = (wid & 1) * 64;

    f32x4 acc[4][4];
    f32x4 zero = {0.f, 0.f, 0.f, 0.f};
#pragma unroll
    for (int m = 0; m < 4; ++m)
#pragma unroll
        for (int n = 0; n < 4; ++n) acc[m][n] = zero;

    const int lrow = lane >> 2;
    const int lcol = (lane & 3) * 8;

    for (int k0 = 0; k0 < K; k0 += 32) {
#pragma unroll
        for (int q = 0; q < 2; ++q) {
            int rbase = wid * 32 + q * 16;
            const unsigned short* gA = A + (size_t)(m0 + rbase + lrow) * K + k0 + lcol;
            gload16(gA, (char*)As + rbase * 64);
            const unsigned short* gB = B + (size_t)(n0 + rbase + lrow) * K + k0 + lcol;
            gload16(gB, (char*)Bs + rbase * 64);
        }
        __syncthreads();
        bf16x8 af[4], bfr[4];
#pragma unroll
        for (int m = 0; m < 4; ++m)
            af[m] = *(const bf16x8*)(As + (waveM + m * 16 + l15) * 32 + lhi * 8);
#pragma unroll
        for (int n = 0; n < 4; ++n)
            bfr[n] = *(const bf16x8*)(Bs + (waveN + n * 16 + l15) * 32 + lhi * 8);
#pragma unroll
        for (int m = 0; m < 4; ++m)
#pragma unroll
            for (int n = 0; n < 4; ++n)
                acc[m][n] = __builtin_amdgcn_mfma_f32_16x16x32_bf16(af[m], bfr[n], acc[m][n], 0, 0, 0);
        __syncthreads();
    }

    if constexpr (MODE == 0) {
#pragma unroll
        for (int n = 0; n < 4; ++n) {
            int col = n0 + waveN + n * 16 + l15;
#pragma unroll
            for (int m = 0; m < 4; ++m) {
                int rowb = m0 + waveM + m * 16 + (lhi << 2);
#pragma unroll
                for (int r = 0; r < 4; ++r)
                    outF[(size_t)(rowb + r) * D_MODEL + col] = acc[m][n][r];
            }
        }
    } else {
        __shared__ unsigned short Ct[4][64][72];
        const int colg0 = n0 + waveN;
        const int hh    = (colg0 >> 6) & (NH - 1);
        const int rowg0 = m0 + waveM;
        const int bb    = rowg0 >> 11;
        const size_t bhh = (size_t)(bb * NH + hh);

#pragma unroll
        for (int n = 0; n < 4; ++n) {
            int cl = n * 16 + l15;
#pragma unroll
            for (int m = 0; m < 4; ++m) {
#pragma unroll
                for (int r = 0; r < 4; ++r) {
                    float v  = acc[m][n][r];
                    float pv = __shfl_xor(v, 1);
                    int rl = m * 16 + (lhi << 2) + r;
                    if (z == 2) {
                        Ct[wid][cl][rl] = f2bf(v);
                    } else {
                        int ss = (rowg0 + rl) & (SEQ - 1);
                        float2 cs = tab[(ss << 5) + (cl >> 1)];
                        float o = (cl & 1) ? (pv * cs.y + v * cs.x)
                                           : (v * cs.x - pv * cs.y);
                        if (z == 0) o *= 0.18033688011f;  // (1/8)*log2(e): exp2-domain softmax
                        Ct[wid][rl][cl] = f2bf(o);
                    }
                }
            }
        }
        asm volatile("s_waitcnt lgkmcnt(0)" ::: "memory");

        const int lr = lane >> 3;
        const int lc = (lane & 7) << 3;
#pragma unroll
        for (int i = 0; i < 8; ++i) {
            int rl = i * 8 + lr;
            uint4 w = *(const uint4*)&Ct[wid][rl][lc];
            if (z == 2) {
                int ss0 = rowg0 & (SEQ - 1);
                *(uint4*)(Vt + (bhh * DK + rl) * SEQ + ss0 + lc) = w;
            } else {
                int ss = (rowg0 + rl) & (SEQ - 1);
                unsigned short* dst = (z == 0) ? Qh : Kh;
                *(uint4*)(dst + (bhh * SEQ + ss) * DK + lc) = w;
            }
        }
    }
}

// ---------------------------------------------------------------------------
// causal flash attention v6:
//  - KV tile 64 (was 128): LDS 40 KB -> 4 blocks/CU = 16 waves/CU (50% occ,
//    was 20%) -- R6 showed VALUBusy 53% at only 2 waves/SIMD (latency-bound)
//  - v_cvt_pk_bf16_f32 packs P pairs in 1 op (was ~4-op f2bf x32 per 128kv)
//  - block = 4 waves, paired q-tiles (pi, 31-pi) -> uniform 33 iters
//  - K/V double-buffered via global_load_lds, both-sides XOR swizzle
//  - one vmcnt(0)+barrier per kv-iteration; prefetch flies across compute
// Qh/Kh: [bh][s][64] bf16 (Q pre-scaled 0.125*log2e); Vt: [bh][64][s] bf16.
// ---------------------------------------------------------------------------
__global__ __launch_bounds__(256) void attn_kernel(
    const unsigned short* __restrict__ Qh,
    const unsigned short* __restrict__ Kh,
    const unsigned short* __restrict__ Vt,
    unsigned short* __restrict__ O)
{
    __shared__ unsigned short Ks[2][64 * 64];   // 8 KB x2
    __shared__ unsigned short Vs[2][64 * 64];   // 8 KB x2
    __shared__ unsigned short P[4][16 * 64];    // 8 KB, per-wave, XOR-swizzled

    const int tid  = threadIdx.x;
    const int lane = tid & 63;
    const int wid  = tid >> 6;
    const int l15 = lane & 15, lhi = lane >> 4;
    const int bh = blockIdx.x;
    const int pi = blockIdx.y;          // pair index 0..15
    const int b = bh >> 4, h = bh & 15;

    const unsigned short* Qb = Qh + (size_t)bh * SEQ * DK;
    const unsigned short* Kb = Kh + (size_t)bh * SEQ * DK;
    const unsigned short* Vb = Vt + (size_t)bh * DK * SEQ;

    // stage one 64-kv tile: K (64 rows x 64d) + V (64 d-rows x 64 kv)
    // 16B units; LDS linear in unit order, global source inverse-swizzled.
    auto STAGE = [&](int buf, int kv0s) {
#pragma unroll
        for (int c = 0; c < 2; ++c) {
            int ub = c * 256 + wid * 64;   // wave-uniform unit base
            int u  = ub + lane;
            int kr = u >> 3;               // K row (0..63)
            int kc = (u & 7) ^ (kr & 7);   // inverse-swizzled col unit
            gload16(Kb + (size_t)(kv0s + kr) * DK + kc * 8, &Ks[buf][(size_t)(ub + lane) * 8 - (size_t)lane * 8 + (size_t)lane * 8]);
        }
#pragma unroll
        for (int c = 0; c < 2; ++c) {
            int ub = c * 256 + wid * 64;
            int u  = ub + lane;
            int vr = u >> 3;               // V d-row (0..63)
            int vc = (u & 7) ^ (vr & 7);
            gload16(Vb + (size_t)vr * SEQ + kv0s + vc * 8, &Vs[buf][(size_t)u * 8]);
        }
    };
    // (note: Ks dest expression simplifies to &Ks[buf][u*8]; kept linear)

    const f32x4 zero = {0.f, 0.f, 0.f, 0.f};
    const f32x4 ninf = {-1e30f, -1e30f, -1e30f, -1e30f};

    STAGE(0, 0);
    int cur = 0;

    for (int ph = 0; ph < 2; ++ph) {
        const int qt = ph ? (31 - pi) : pi;
        const int ktl = qt;                 // last 64-wide kv tile
        const int q0 = qt * 64;
        const int qw = q0 + wid * 16;

        bf16x8 qf[2];
#pragma unroll
        for (int kk = 0; kk < 2; ++kk)
            qf[kk] = *(const bf16x8*)(Qb + (size_t)(qw + l15) * DK + kk * 32 + lhi * 8);

        f32x4 oacc[4];
#pragma unroll
        for (int nd = 0; nd < 4; ++nd) oacc[nd] = zero;
        float mrow = -1e30f;
        float lrow = 0.f;

        for (int kt = 0; kt <= ktl; ++kt) {
            const int kv0 = kt << 6;
            const bool diag = (kt == ktl);
            const int nlim = diag ? (wid + 1) : 4;

            asm volatile("s_waitcnt vmcnt(0)" ::: "memory");
            __builtin_amdgcn_s_barrier();
            __builtin_amdgcn_sched_barrier(0);

            const bool hasNext = (kt < ktl) || (ph == 0);
            if (hasNext) STAGE(cur ^ 1, (kt < ktl) ? (kv0 + 64) : 0);

            f32x4 s[4];  // s[n][r]: k = kv0+n*16+(lhi<<2)+r, q = qw+l15
#pragma unroll
            for (int n = 0; n < 4; ++n) s[n] = (n < nlim) ? zero : ninf;

            const int sw = l15 & 7;
            __builtin_amdgcn_s_setprio(1);
#pragma unroll
            for (int n = 0; n < 4; ++n) {
                if (n < nlim) {
                    int r = n * 16 + l15;
                    bf16x8 k0 = *(const bf16x8*)&Ks[cur][r * 64 + ((lhi ^ sw) << 3)];
                    bf16x8 k1 = *(const bf16x8*)&Ks[cur][r * 64 + (((4 + lhi) ^ sw) << 3)];
                    s[n] = __builtin_amdgcn_mfma_f32_16x16x32_bf16(k0, qf[0], s[n], 0, 0, 0);
                    s[n] = __builtin_amdgcn_mfma_f32_16x16x32_bf16(k1, qf[1], s[n], 0, 0, 0);
                }
            }
            __builtin_amdgcn_s_setprio(0);

            if (diag) {  // causal: mask k > q
                const int qg = qw + l15;
#pragma unroll
                for (int n = 0; n < 4; ++n) {
                    if (n < nlim) {
#pragma unroll
                        for (int r = 0; r < 4; ++r) {
                            int kg = kv0 + n * 16 + (lhi << 2) + r;
                            if (kg > qg) s[n][r] = -1e30f;
                        }
                    }
                }
            }

            // row max: local tree + 2 shfls
            float mx = fmaxf(fmaxf(s[0][0], s[0][1]), fmaxf(s[0][2], s[0][3]));
#pragma unroll
            for (int n = 1; n < 4; ++n)
                mx = fmaxf(mx, fmaxf(fmaxf(s[n][0], s[n][1]), fmaxf(s[n][2], s[n][3])));
            mx = fmaxf(mx, __shfl_xor(mx, 16));
            mx = fmaxf(mx, __shfl_xor(mx, 32));

            float alpha = 1.f;
            const int allDefer = __all(mx <= mrow + 8.f);
            if (!allDefer) {
                float mn = fmaxf(mrow, mx);
                alpha = __builtin_amdgcn_exp2f(mrow - mn);
                mrow = mn;
            }

#pragma unroll
            for (int n = 0; n < 4; ++n)
#pragma unroll
                for (int r = 0; r < 4; ++r)
                    s[n][r] = __builtin_amdgcn_exp2f(s[n][r] - mrow);

            float rs = 0.f;
#pragma unroll
            for (int n = 0; n < 4; ++n)
                rs += (s[n][0] + s[n][1]) + (s[n][2] + s[n][3]);
            rs += __shfl_xor(rs, 16);
            rs += __shfl_xor(rs, 32);
            lrow = allDefer ? (lrow + rs) : (lrow * alpha + rs);

            // P -> LDS: v_cvt_pk_bf16_f32 pairs + ds_write_b64, XOR-swizzled
#pragma unroll
            for (int n = 0; n < 4; ++n) {
                uint2 pk;
                pk.x = cvtpk(s[n][0], s[n][1]);
                pk.y = cvtpk(s[n][2], s[n][3]);
                int cW = 2 * n + (lhi >> 1);
                *(uint2*)&P[wid][(l15 << 6) + ((cW ^ sw) << 3) + ((lhi & 1) << 2)] = pk;
            }

            if (!allDefer) {
                float a0 = __shfl(alpha, (lhi << 2) + 0);
                float a1 = __shfl(alpha, (lhi << 2) + 1);
                float a2 = __shfl(alpha, (lhi << 2) + 2);
                float a3 = __shfl(alpha, (lhi << 2) + 3);
#pragma unroll
                for (int nd = 0; nd < 4; ++nd) {
                    oacc[nd][0] *= a0; oacc[nd][1] *= a1;
                    oacc[nd][2] *= a2; oacc[nd][3] *= a3;
                }
            }

            asm volatile("s_waitcnt lgkmcnt(0)" ::: "memory");
            const int kklim = diag ? ((nlim + 1) >> 1) : 2;
            bf16x8 pa[2];
#pragma unroll
            for (int kk = 0; kk < 2; ++kk)
                if (kk < kklim)
                    pa[kk] = *(const bf16x8*)&P[wid][(l15 << 6) + ((((kk << 2) + lhi) ^ sw) << 3)];

            __builtin_amdgcn_s_setprio(1);
#pragma unroll
            for (int nd = 0; nd < 4; ++nd)
#pragma unroll
                for (int kk = 0; kk < 2; ++kk)
                    if (kk < kklim) {
                        int rd = nd * 16 + l15;
                        bf16x8 vf = *(const bf16x8*)&Vs[cur][rd * 64 + ((((kk << 2) + lhi) ^ sw) << 3)];
                        oacc[nd] = __builtin_amdgcn_mfma_f32_16x16x32_bf16(pa[kk], vf, oacc[nd], 0, 0, 0);
                    }
            __builtin_amdgcn_s_setprio(0);

            cur ^= 1;
        }

        float inv = 1.f / lrow;
        float i0 = __shfl(inv, (lhi << 2) + 0);
        float i1 = __shfl(inv, (lhi << 2) + 1);
        float i2 = __shfl(inv, (lhi << 2) + 2);
        float i3 = __shfl(inv, (lhi << 2) + 3);
#pragma unroll
        for (int nd = 0; nd < 4; ++nd) {
            int d = nd * 16 + l15;
            int rowb = qw + (lhi << 2);
            O[((size_t)(b * SEQ + rowb + 0)) * D_MODEL + h * DK + d] = f2bf(oacc[nd][0] * i0);
            O[((size_t)(b * SEQ + rowb + 1)) * D_MODEL + h * DK + d] = f2bf(oacc[nd][1] * i1);
            O[((size_t)(b * SEQ + rowb + 2)) * D_MODEL + h * DK + d] = f2bf(oacc[nd][2] * i2);
            O[((size_t)(b * SEQ + rowb + 3)) * D_MODEL + h * DK + d] = f2bf(oacc[nd][3] * i3);
        }
    }
}

// ---------------------------------------------------------------------------
extern "C" void kernel_launch(void* const* d_in, const int* in_sizes, int n_in,
                              void* d_out, int out_size, void* d_ws, size_t ws_size,
                              hipStream_t stream)
{
    const float* x  = (const float*)d_in[0];
    const float* Wq = (const float*)d_in[1];
    const float* Wk = (const float*)d_in[2];
    const float* Wv = (const float*)d_in[3];
    const float* Wo = (const float*)d_in[4];
    float* out = (float*)d_out;

    char* ws = (char*)d_ws;
    unsigned short* xb  = (unsigned short*)(ws);                    // 8 MB (reused as attn buf)
    unsigned short* Wqb = (unsigned short*)(ws + ( 8ull << 20));
    unsigned short* Wkb = (unsigned short*)(ws + (10ull << 20));
    unsigned short* Wvb = (unsigned short*)(ws + (12ull << 20));
    unsigned short* Wob = (unsigned short*)(ws + (14ull << 20));
    unsigned short* Qh  = (unsigned short*)(ws + (16ull << 20));    // [bh][s][64]
    unsigned short* Kh  = (unsigned short*)(ws + (24ull << 20));    // [bh][s][64]
    unsigned short* Vt  = (unsigned short*)(ws + (32ull << 20));    // [bh][64][s]
    float2*         tab = (float2*)(ws + (40ull << 20));            // 512 KB RoPE table
    unsigned short* attn = xb;

    cast5<<<dim3(512, 6), 256, 0, stream>>>(x, Wq, Wk, Wv, Wo, xb, Wqb, Wkb, Wvb, Wob, tab);

    gemm_bt<1><<<dim3(D_MODEL / 128, (NB * SEQ) / 128, 3), 256, 0, stream>>>(
        xb, Wqb, Wkb, Wvb, nullptr, Qh, Kh, Vt, tab, NB * SEQ, D_MODEL);

    attn_kernel<<<dim3(NB * NH, 16), 256, 0, stream>>>(Qh, Kh, Vt, attn);

    gemm_bt<0><<<dim3(D_MODEL / 128, (NB * SEQ) / 128, 1), 256, 0, stream>>>(
        attn, Wob, Wob, Wob, out, nullptr, nullptr, nullptr, nullptr, NB * SEQ, D_MODEL);
}

// Round 8
// 118.898 us; speedup vs baseline: 1.7306x; 1.0975x over previous
//
#include <hip/hip_runtime.h>

typedef float f32x4 __attribute__((ext_vector_type(4)));
typedef __bf16 bf16x8 __attribute__((ext_vector_type(8)));

#define D_MODEL 1024
#define SEQ     2048
#define NB      2
#define NH      16
#define DK      64

__device__ __forceinline__ unsigned short f2bf(float f) {
    union { float f; unsigned int u; } un; un.f = f;
    unsigned int r = un.u + 0x7fffu + ((un.u >> 16) & 1u);
    return (unsigned short)(r >> 16);
}

__device__ __forceinline__ unsigned cvtpk(float lo, float hi) {
    unsigned r;
    asm("v_cvt_pk_bf16_f32 %0, %1, %2" : "=v"(r) : "v"(lo), "v"(hi));
    return r;
}

__device__ __forceinline__ void gload16(const void* g, void* l) {
    __builtin_amdgcn_global_load_lds((__attribute__((address_space(1))) void*)g,
                                     (__attribute__((address_space(3))) void*)l,
                                     16, 0, 0);
}

// ---------------------------------------------------------------------------
// fused fp32 -> bf16 casts for x and the 4 weights + RoPE cos/sin table
// ---------------------------------------------------------------------------
__global__ __launch_bounds__(256) void cast5(
    const float* __restrict__ x,  const float* __restrict__ wq,
    const float* __restrict__ wk, const float* __restrict__ wv,
    const float* __restrict__ wo,
    unsigned short* __restrict__ xb,  unsigned short* __restrict__ wqb,
    unsigned short* __restrict__ wkb, unsigned short* __restrict__ wvb,
    unsigned short* __restrict__ wob, float2* __restrict__ tab)
{
    if (blockIdx.y == 5) {  // RoPE table: [ss][p] -> (cos, sin), p = d/2 index
        int idx = blockIdx.x * 256 + threadIdx.x;
        if (idx < SEQ * 32) {
            int ss = idx >> 5, p = idx & 31;
            float freq = exp2f(-0.41524101186f * (float)p);  // 10000^(-p/32)
            float sn, cs;
            sincosf((float)ss * freq, &sn, &cs);
            tab[idx] = make_float2(cs, sn);
        }
        return;
    }
    const float* src; unsigned short* dst; int n8;
    switch (blockIdx.y) {
        case 0:  src = x;  dst = xb;  n8 = (NB*SEQ*D_MODEL)/8; break;
        case 1:  src = wq; dst = wqb; n8 = (D_MODEL*D_MODEL)/8; break;
        case 2:  src = wk; dst = wkb; n8 = (D_MODEL*D_MODEL)/8; break;
        case 3:  src = wv; dst = wvb; n8 = (D_MODEL*D_MODEL)/8; break;
        default: src = wo; dst = wob; n8 = (D_MODEL*D_MODEL)/8; break;
    }
    int stride = gridDim.x * blockDim.x;
    for (int i = blockIdx.x * blockDim.x + threadIdx.x; i < n8; i += stride) {
        const float4* p = (const float4*)src + (size_t)i * 2;
        float4 a = p[0], b = p[1];
        union { unsigned short h[8]; uint4 v; } u;
        u.h[0] = f2bf(a.x); u.h[1] = f2bf(a.y); u.h[2] = f2bf(a.z); u.h[3] = f2bf(a.w);
        u.h[4] = f2bf(b.x); u.h[5] = f2bf(b.y); u.h[6] = f2bf(b.z); u.h[7] = f2bf(b.w);
        ((uint4*)dst)[i] = u.v;
    }
}

// ---------------------------------------------------------------------------
// GEMM  C[M][1024] = A[M][K](bf16) * B[1024][K]^T (bf16, weights are [out][in])
// v2: triple-buffered LDS + 2-deep prefetch + counted vmcnt(4) (attn-proven
// pipeline; R7 showed the old issue-then-drain loop left MFMA at 5% issue).
// MODE 0: plain fp32 write to outF
// MODE 1: QKV fused: RoPE via table on Q(z=0, scaled by 0.125*log2e) and
//   K(z=1) -> [bh][s][64]; V(z=2) -> [bh][64][s]. Epilogue stages each
//   wave's 64x64 bf16 tile in LDS (ALIASED onto the stage buffers) for
//   full-128B-line stores.
// ---------------------------------------------------------------------------
template <int MODE>
__global__ __launch_bounds__(256) void gemm_bt(
    const unsigned short* __restrict__ A,
    const unsigned short* __restrict__ B0,
    const unsigned short* __restrict__ B1,
    const unsigned short* __restrict__ B2,
    float* __restrict__ outF,
    unsigned short* __restrict__ Qh,
    unsigned short* __restrict__ Kh,
    unsigned short* __restrict__ Vt,
    const float2* __restrict__ tab,
    int M, int K)
{
    // [buf][A=0/B=1][128 rows x 32 cols]; 48 KB. MODE 1 epilogue aliases it.
    __shared__ __align__(16) unsigned short SM[3][2][128 * 32];

    const int lane = threadIdx.x & 63;
    const int wid  = threadIdx.x >> 6;
    const int l15 = lane & 15, lhi = lane >> 4;
    const int m0 = blockIdx.y * 128;
    const int n0 = blockIdx.x * 128;
    const int z  = (MODE == 1) ? (int)blockIdx.z : 0;
    const unsigned short* B = (z == 0) ? B0 : (z == 1) ? B1 : B2;
    const int waveM = (wid >> 1) * 64;
    const int waveN = (wid & 1) * 64;

    f32x4 acc[4][4];
    f32x4 zero = {0.f, 0.f, 0.f, 0.f};
#pragma unroll
    for (int m = 0; m < 4; ++m)
#pragma unroll
        for (int n = 0; n < 4; ++n) acc[m][n] = zero;

    const int lrow = lane >> 2;       // row within 16-row staging chunk
    const int lcol = (lane & 3) * 8;  // element offset within row

    // stage K-step k0 into buffer buf: per wave 2x16 rows of A and of B
    auto STAGE = [&](int buf, int k0) {
#pragma unroll
        for (int q = 0; q < 2; ++q) {
            int rbase = wid * 32 + q * 16;
            gload16(A + (size_t)(m0 + rbase + lrow) * K + k0 + lcol,
                    (char*)&SM[buf][0][0] + rbase * 64);
            gload16(B + (size_t)(n0 + rbase + lrow) * K + k0 + lcol,
                    (char*)&SM[buf][1][0] + rbase * 64);
        }
    };

    const int NK = K >> 5;            // 32 K-steps
    STAGE(0, 0);
    STAGE(1, 32);

    for (int k = 0; k < NK; ++k) {
        if (k < NK - 1) asm volatile("s_waitcnt vmcnt(4)" ::: "memory");
        else            asm volatile("s_waitcnt vmcnt(0)" ::: "memory");
        __builtin_amdgcn_s_barrier();
        __builtin_amdgcn_sched_barrier(0);
        if (k + 2 < NK) STAGE((k + 2) % 3, (k + 2) << 5);

        const unsigned short* as = SM[k % 3][0];
        const unsigned short* bs = SM[k % 3][1];
        bf16x8 af[4], bfr[4];
#pragma unroll
        for (int m = 0; m < 4; ++m)
            af[m] = *(const bf16x8*)(as + (waveM + m * 16 + l15) * 32 + lhi * 8);
#pragma unroll
        for (int n = 0; n < 4; ++n)
            bfr[n] = *(const bf16x8*)(bs + (waveN + n * 16 + l15) * 32 + lhi * 8);
        __builtin_amdgcn_s_setprio(1);
#pragma unroll
        for (int m = 0; m < 4; ++m)
#pragma unroll
            for (int n = 0; n < 4; ++n)
                acc[m][n] = __builtin_amdgcn_mfma_f32_16x16x32_bf16(af[m], bfr[n], acc[m][n], 0, 0, 0);
        __builtin_amdgcn_s_setprio(0);
    }

    if constexpr (MODE == 0) {
#pragma unroll
        for (int n = 0; n < 4; ++n) {
            int col = n0 + waveN + n * 16 + l15;
#pragma unroll
            for (int m = 0; m < 4; ++m) {
                int rowb = m0 + waveM + m * 16 + (lhi << 2);
#pragma unroll
                for (int r = 0; r < 4; ++r)
                    outF[(size_t)(rowb + r) * D_MODEL + col] = acc[m][n][r];
            }
        }
    } else {
        __syncthreads();  // all waves done with stage buffers before aliasing
        unsigned short* Ct = ((unsigned short*)SM) + wid * 4608;  // 64x72/wave
        const int colg0 = n0 + waveN;
        const int hh    = (colg0 >> 6) & (NH - 1);
        const int rowg0 = m0 + waveM;
        const int bb    = rowg0 >> 11;
        const size_t bhh = (size_t)(bb * NH + hh);

#pragma unroll
        for (int n = 0; n < 4; ++n) {
            int cl = n * 16 + l15;
#pragma unroll
            for (int m = 0; m < 4; ++m) {
#pragma unroll
                for (int r = 0; r < 4; ++r) {
                    float v  = acc[m][n][r];
                    float pv = __shfl_xor(v, 1);
                    int rl = m * 16 + (lhi << 2) + r;
                    if (z == 2) {
                        Ct[cl * 72 + rl] = f2bf(v);
                    } else {
                        int ss = (rowg0 + rl) & (SEQ - 1);
                        float2 cs = tab[(ss << 5) + (cl >> 1)];
                        float o = (cl & 1) ? (pv * cs.y + v * cs.x)
                                           : (v * cs.x - pv * cs.y);
                        if (z == 0) o *= 0.18033688011f;  // (1/8)*log2(e)
                        Ct[rl * 72 + cl] = f2bf(o);
                    }
                }
            }
        }
        asm volatile("s_waitcnt lgkmcnt(0)" ::: "memory");

        const int lr = lane >> 3;
        const int lc = (lane & 7) << 3;
#pragma unroll
        for (int i = 0; i < 8; ++i) {
            int rl = i * 8 + lr;
            uint4 w = *(const uint4*)&Ct[rl * 72 + lc];
            if (z == 2) {
                int ss0 = rowg0 & (SEQ - 1);
                *(uint4*)(Vt + (bhh * DK + rl) * SEQ + ss0 + lc) = w;
            } else {
                int ss = (rowg0 + rl) & (SEQ - 1);
                unsigned short* dst = (z == 0) ? Qh : Kh;
                *(uint4*)(dst + (bhh * SEQ + ss) * DK + lc) = w;
            }
        }
    }
}

// ---------------------------------------------------------------------------
// causal flash attention v6 (unchanged from R7):
//  - KV tile 64: LDS 40 KB -> 4 blocks/CU
//  - v_cvt_pk_bf16_f32 P packing; paired q-tiles (pi, 31-pi)
//  - K/V double-buffered via global_load_lds, both-sides XOR swizzle
//  - one vmcnt(0)+barrier per kv-iteration; prefetch flies across compute
// ---------------------------------------------------------------------------
__global__ __launch_bounds__(256) void attn_kernel(
    const unsigned short* __restrict__ Qh,
    const unsigned short* __restrict__ Kh,
    const unsigned short* __restrict__ Vt,
    unsigned short* __restrict__ O)
{
    __shared__ unsigned short Ks[2][64 * 64];
    __shared__ unsigned short Vs[2][64 * 64];
    __shared__ unsigned short P[4][16 * 64];

    const int tid  = threadIdx.x;
    const int lane = tid & 63;
    const int wid  = tid >> 6;
    const int l15 = lane & 15, lhi = lane >> 4;
    const int bh = blockIdx.x;
    const int pi = blockIdx.y;
    const int b = bh >> 4, h = bh & 15;

    const unsigned short* Qb = Qh + (size_t)bh * SEQ * DK;
    const unsigned short* Kb = Kh + (size_t)bh * SEQ * DK;
    const unsigned short* Vb = Vt + (size_t)bh * DK * SEQ;

    auto STAGE = [&](int buf, int kv0s) {
#pragma unroll
        for (int c = 0; c < 2; ++c) {
            int ub = c * 256 + wid * 64;
            int u  = ub + lane;
            int kr = u >> 3;
            int kc = (u & 7) ^ (kr & 7);
            gload16(Kb + (size_t)(kv0s + kr) * DK + kc * 8, &Ks[buf][(size_t)ub * 8]);
        }
#pragma unroll
        for (int c = 0; c < 2; ++c) {
            int ub = c * 256 + wid * 64;
            int u  = ub + lane;
            int vr = u >> 3;
            int vc = (u & 7) ^ (vr & 7);
            gload16(Vb + (size_t)vr * SEQ + kv0s + vc * 8, &Vs[buf][(size_t)ub * 8]);
        }
    };

    const f32x4 zero = {0.f, 0.f, 0.f, 0.f};
    const f32x4 ninf = {-1e30f, -1e30f, -1e30f, -1e30f};

    STAGE(0, 0);
    int cur = 0;

    for (int ph = 0; ph < 2; ++ph) {
        const int qt = ph ? (31 - pi) : pi;
        const int ktl = qt;
        const int q0 = qt * 64;
        const int qw = q0 + wid * 16;

        bf16x8 qf[2];
#pragma unroll
        for (int kk = 0; kk < 2; ++kk)
            qf[kk] = *(const bf16x8*)(Qb + (size_t)(qw + l15) * DK + kk * 32 + lhi * 8);

        f32x4 oacc[4];
#pragma unroll
        for (int nd = 0; nd < 4; ++nd) oacc[nd] = zero;
        float mrow = -1e30f;
        float lrow = 0.f;

        for (int kt = 0; kt <= ktl; ++kt) {
            const int kv0 = kt << 6;
            const bool diag = (kt == ktl);
            const int nlim = diag ? (wid + 1) : 4;

            asm volatile("s_waitcnt vmcnt(0)" ::: "memory");
            __builtin_amdgcn_s_barrier();
            __builtin_amdgcn_sched_barrier(0);

            const bool hasNext = (kt < ktl) || (ph == 0);
            if (hasNext) STAGE(cur ^ 1, (kt < ktl) ? (kv0 + 64) : 0);

            f32x4 s[4];
#pragma unroll
            for (int n = 0; n < 4; ++n) s[n] = (n < nlim) ? zero : ninf;

            const int sw = l15 & 7;
            __builtin_amdgcn_s_setprio(1);
#pragma unroll
            for (int n = 0; n < 4; ++n) {
                if (n < nlim) {
                    int r = n * 16 + l15;
                    bf16x8 k0 = *(const bf16x8*)&Ks[cur][r * 64 + ((lhi ^ sw) << 3)];
                    bf16x8 k1 = *(const bf16x8*)&Ks[cur][r * 64 + (((4 + lhi) ^ sw) << 3)];
                    s[n] = __builtin_amdgcn_mfma_f32_16x16x32_bf16(k0, qf[0], s[n], 0, 0, 0);
                    s[n] = __builtin_amdgcn_mfma_f32_16x16x32_bf16(k1, qf[1], s[n], 0, 0, 0);
                }
            }
            __builtin_amdgcn_s_setprio(0);

            if (diag) {
                const int qg = qw + l15;
#pragma unroll
                for (int n = 0; n < 4; ++n) {
                    if (n < nlim) {
#pragma unroll
                        for (int r = 0; r < 4; ++r) {
                            int kg = kv0 + n * 16 + (lhi << 2) + r;
                            if (kg > qg) s[n][r] = -1e30f;
                        }
                    }
                }
            }

            float mx = fmaxf(fmaxf(s[0][0], s[0][1]), fmaxf(s[0][2], s[0][3]));
#pragma unroll
            for (int n = 1; n < 4; ++n)
                mx = fmaxf(mx, fmaxf(fmaxf(s[n][0], s[n][1]), fmaxf(s[n][2], s[n][3])));
            mx = fmaxf(mx, __shfl_xor(mx, 16));
            mx = fmaxf(mx, __shfl_xor(mx, 32));

            float alpha = 1.f;
            const int allDefer = __all(mx <= mrow + 8.f);
            if (!allDefer) {
                float mn = fmaxf(mrow, mx);
                alpha = __builtin_amdgcn_exp2f(mrow - mn);
                mrow = mn;
            }

#pragma unroll
            for (int n = 0; n < 4; ++n)
#pragma unroll
                for (int r = 0; r < 4; ++r)
                    s[n][r] = __builtin_amdgcn_exp2f(s[n][r] - mrow);

            float rs = 0.f;
#pragma unroll
            for (int n = 0; n < 4; ++n)
                rs += (s[n][0] + s[n][1]) + (s[n][2] + s[n][3]);
            rs += __shfl_xor(rs, 16);
            rs += __shfl_xor(rs, 32);
            lrow = allDefer ? (lrow + rs) : (lrow * alpha + rs);

#pragma unroll
            for (int n = 0; n < 4; ++n) {
                uint2 pk;
                pk.x = cvtpk(s[n][0], s[n][1]);
                pk.y = cvtpk(s[n][2], s[n][3]);
                int cW = 2 * n + (lhi >> 1);
                *(uint2*)&P[wid][(l15 << 6) + ((cW ^ sw) << 3) + ((lhi & 1) << 2)] = pk;
            }

            if (!allDefer) {
                float a0 = __shfl(alpha, (lhi << 2) + 0);
                float a1 = __shfl(alpha, (lhi << 2) + 1);
                float a2 = __shfl(alpha, (lhi << 2) + 2);
                float a3 = __shfl(alpha, (lhi << 2) + 3);
#pragma unroll
                for (int nd = 0; nd < 4; ++nd) {
                    oacc[nd][0] *= a0; oacc[nd][1] *= a1;
                    oacc[nd][2] *= a2; oacc[nd][3] *= a3;
                }
            }

            asm volatile("s_waitcnt lgkmcnt(0)" ::: "memory");
            const int kklim = diag ? ((nlim + 1) >> 1) : 2;
            bf16x8 pa[2];
#pragma unroll
            for (int kk = 0; kk < 2; ++kk)
                if (kk < kklim)
                    pa[kk] = *(const bf16x8*)&P[wid][(l15 << 6) + ((((kk << 2) + lhi) ^ sw) << 3)];

            __builtin_amdgcn_s_setprio(1);
#pragma unroll
            for (int nd = 0; nd < 4; ++nd)
#pragma unroll
                for (int kk = 0; kk < 2; ++kk)
                    if (kk < kklim) {
                        int rd = nd * 16 + l15;
                        bf16x8 vf = *(const bf16x8*)&Vs[cur][rd * 64 + ((((kk << 2) + lhi) ^ sw) << 3)];
                        oacc[nd] = __builtin_amdgcn_mfma_f32_16x16x32_bf16(pa[kk], vf, oacc[nd], 0, 0, 0);
                    }
            __builtin_amdgcn_s_setprio(0);

            cur ^= 1;
        }

        float inv = 1.f / lrow;
        float i0 = __shfl(inv, (lhi << 2) + 0);
        float i1 = __shfl(inv, (lhi << 2) + 1);
        float i2 = __shfl(inv, (lhi << 2) + 2);
        float i3 = __shfl(inv, (lhi << 2) + 3);
#pragma unroll
        for (int nd = 0; nd < 4; ++nd) {
            int d = nd * 16 + l15;
            int rowb = qw + (lhi << 2);
            O[((size_t)(b * SEQ + rowb + 0)) * D_MODEL + h * DK + d] = f2bf(oacc[nd][0] * i0);
            O[((size_t)(b * SEQ + rowb + 1)) * D_MODEL + h * DK + d] = f2bf(oacc[nd][1] * i1);
            O[((size_t)(b * SEQ + rowb + 2)) * D_MODEL + h * DK + d] = f2bf(oacc[nd][2] * i2);
            O[((size_t)(b * SEQ + rowb + 3)) * D_MODEL + h * DK + d] = f2bf(oacc[nd][3] * i3);
        }
    }
}

// ---------------------------------------------------------------------------
extern "C" void kernel_launch(void* const* d_in, const int* in_sizes, int n_in,
                              void* d_out, int out_size, void* d_ws, size_t ws_size,
                              hipStream_t stream)
{
    const float* x  = (const float*)d_in[0];
    const float* Wq = (const float*)d_in[1];
    const float* Wk = (const float*)d_in[2];
    const float* Wv = (const float*)d_in[3];
    const float* Wo = (const float*)d_in[4];
    float* out = (float*)d_out;

    char* ws = (char*)d_ws;
    unsigned short* xb  = (unsigned short*)(ws);                    // 8 MB (reused as attn buf)
    unsigned short* Wqb = (unsigned short*)(ws + ( 8ull << 20));
    unsigned short* Wkb = (unsigned short*)(ws + (10ull << 20));
    unsigned short* Wvb = (unsigned short*)(ws + (12ull << 20));
    unsigned short* Wob = (unsigned short*)(ws + (14ull << 20));
    unsigned short* Qh  = (unsigned short*)(ws + (16ull << 20));    // [bh][s][64]
    unsigned short* Kh  = (unsigned short*)(ws + (24ull << 20));    // [bh][s][64]
    unsigned short* Vt  = (unsigned short*)(ws + (32ull << 20));    // [bh][64][s]
    float2*         tab = (float2*)(ws + (40ull << 20));            // 512 KB RoPE table
    unsigned short* attn = xb;

    cast5<<<dim3(512, 6), 256, 0, stream>>>(x, Wq, Wk, Wv, Wo, xb, Wqb, Wkb, Wvb, Wob, tab);

    gemm_bt<1><<<dim3(D_MODEL / 128, (NB * SEQ) / 128, 3), 256, 0, stream>>>(
        xb, Wqb, Wkb, Wvb, nullptr, Qh, Kh, Vt, tab, NB * SEQ, D_MODEL);

    attn_kernel<<<dim3(NB * NH, 16), 256, 0, stream>>>(Qh, Kh, Vt, attn);

    gemm_bt<0><<<dim3(D_MODEL / 128, (NB * SEQ) / 128, 1), 256, 0, stream>>>(
        attn, Wob, Wob, Wob, out, nullptr, nullptr, nullptr, nullptr, NB * SEQ, D_MODEL);
}

// Round 9
// 116.707 us; speedup vs baseline: 1.7630x; 1.0188x over previous
//
#include <hip/hip_runtime.h>

typedef float f32x4 __attribute__((ext_vector_type(4)));
typedef __bf16 bf16x8 __attribute__((ext_vector_type(8)));

#define D_MODEL 1024
#define SEQ     2048
#define NB      2
#define NH      16
#define DK      64

__device__ __forceinline__ unsigned short f2bf(float f) {
    union { float f; unsigned int u; } un; un.f = f;
    unsigned int r = un.u + 0x7fffu + ((un.u >> 16) & 1u);
    return (unsigned short)(r >> 16);
}

__device__ __forceinline__ unsigned cvtpk(float lo, float hi) {
    unsigned r;
    asm("v_cvt_pk_bf16_f32 %0, %1, %2" : "=v"(r) : "v"(lo), "v"(hi));
    return r;
}

__device__ __forceinline__ void gload16(const void* g, void* l) {
    __builtin_amdgcn_global_load_lds((__attribute__((address_space(1))) void*)g,
                                     (__attribute__((address_space(3))) void*)l,
                                     16, 0, 0);
}

// ---------------------------------------------------------------------------
// fused fp32 -> bf16 casts for x and the 4 weights + RoPE cos/sin table
// ---------------------------------------------------------------------------
__global__ __launch_bounds__(256) void cast5(
    const float* __restrict__ x,  const float* __restrict__ wq,
    const float* __restrict__ wk, const float* __restrict__ wv,
    const float* __restrict__ wo,
    unsigned short* __restrict__ xb,  unsigned short* __restrict__ wqb,
    unsigned short* __restrict__ wkb, unsigned short* __restrict__ wvb,
    unsigned short* __restrict__ wob, float2* __restrict__ tab)
{
    if (blockIdx.y == 5) {  // RoPE table: [ss][p] -> (cos, sin), p = d/2 index
        int idx = blockIdx.x * 256 + threadIdx.x;
        if (idx < SEQ * 32) {
            int ss = idx >> 5, p = idx & 31;
            float freq = exp2f(-0.41524101186f * (float)p);  // 10000^(-p/32)
            float sn, cs;
            sincosf((float)ss * freq, &sn, &cs);
            tab[idx] = make_float2(cs, sn);
        }
        return;
    }
    const float* src; unsigned short* dst; int n8;
    switch (blockIdx.y) {
        case 0:  src = x;  dst = xb;  n8 = (NB*SEQ*D_MODEL)/8; break;
        case 1:  src = wq; dst = wqb; n8 = (D_MODEL*D_MODEL)/8; break;
        case 2:  src = wk; dst = wkb; n8 = (D_MODEL*D_MODEL)/8; break;
        case 3:  src = wv; dst = wvb; n8 = (D_MODEL*D_MODEL)/8; break;
        default: src = wo; dst = wob; n8 = (D_MODEL*D_MODEL)/8; break;
    }
    int stride = gridDim.x * blockDim.x;
    for (int i = blockIdx.x * blockDim.x + threadIdx.x; i < n8; i += stride) {
        const float4* p = (const float4*)src + (size_t)i * 2;
        float4 a = p[0], b = p[1];
        union { unsigned short h[8]; uint4 v; } u;
        u.h[0] = f2bf(a.x); u.h[1] = f2bf(a.y); u.h[2] = f2bf(a.z); u.h[3] = f2bf(a.w);
        u.h[4] = f2bf(b.x); u.h[5] = f2bf(b.y); u.h[6] = f2bf(b.z); u.h[7] = f2bf(b.w);
        ((uint4*)dst)[i] = u.v;
    }
}

// ---------------------------------------------------------------------------
// GEMM  C[M][1024] = A[M][K](bf16) * B[1024][K]^T (bf16, weights are [out][in])
// Triple-buffered LDS + 2-deep prefetch + counted vmcnt.
// 1-D launch with A-panel XCD clustering: launch index L -> (x,y,z) such
// that L%8 == y%8, so all blocks sharing an A-panel land on ONE XCD and A
// stages hit L2 (R8: default mapping spread panels over 8 XCDs -> 58 MB of
// redundant HBM A-fetch at ~900cyc latency on the vmcnt critical path).
// MODE 0 (BM=64, BN=128 -> 512 blocks, 2/CU): plain fp32 write to outF
// MODE 1 (BM=BN=128 -> 768 blocks, 3/CU): QKV fused, RoPE epilogue via LDS.
// ---------------------------------------------------------------------------
template <int MODE, int BM, int BN>
__global__ __launch_bounds__(256) void gemm_bt(
    const unsigned short* __restrict__ A,
    const unsigned short* __restrict__ B0,
    const unsigned short* __restrict__ B1,
    const unsigned short* __restrict__ B2,
    float* __restrict__ outF,
    unsigned short* __restrict__ Qh,
    unsigned short* __restrict__ Kh,
    unsigned short* __restrict__ Vt,
    const float2* __restrict__ tab,
    int M, int K)
{
    constexpr int PER_STAGE = (BM + BN) / 64;   // gload16 per thread per stage
    constexpr int WM = BM / 2, WN = BN / 2;
    constexpr int FM = WM / 16, FN = WN / 16;
    __shared__ __align__(16) unsigned short SM[3 * (BM + BN) * 32];

    const int lane = threadIdx.x & 63;
    const int wid  = threadIdx.x >> 6;
    const int l15 = lane & 15, lhi = lane >> 4;

    // ---- block swizzle decode: L = (y&7) + 8*(x + 8*(y>>3) + 32*z) ----
    const int L  = blockIdx.x;
    const int yl = L & 7;
    const int t  = L >> 3;
    const int bx = t & 7;
    const int t2 = t >> 3;
    int y, z;
    if constexpr (MODE == 1) { y = ((t2 & 3) << 3) | yl; z = t2 >> 2; }
    else                     { y = (t2 << 3) | yl;       z = 0;       }
    const int m0 = y * BM;
    const int n0 = bx * BN;
    const unsigned short* B = (z == 0) ? B0 : (z == 1) ? B1 : B2;
    const int waveM = (wid >> 1) * WM;
    const int waveN = (wid & 1) * WN;

    f32x4 acc[FM][FN];
    f32x4 zero = {0.f, 0.f, 0.f, 0.f};
#pragma unroll
    for (int m = 0; m < FM; ++m)
#pragma unroll
        for (int n = 0; n < FN; ++n) acc[m][n] = zero;

    const int lrow = lane >> 2;       // row within 16-row staging chunk
    const int lcol = (lane & 3) * 8;  // element offset within row

    auto STAGE = [&](int buf, int k0) {
        unsigned short* as = SM + buf * (BM + BN) * 32;
        unsigned short* bs = as + BM * 32;
#pragma unroll
        for (int q = 0; q < BM / 64; ++q) {
            int rbase = wid * (BM / 4) + q * 16;
            gload16(A + (size_t)(m0 + rbase + lrow) * K + k0 + lcol,
                    (char*)as + rbase * 64);
        }
#pragma unroll
        for (int q = 0; q < BN / 64; ++q) {
            int rbase = wid * (BN / 4) + q * 16;
            gload16(B + (size_t)(n0 + rbase + lrow) * K + k0 + lcol,
                    (char*)bs + rbase * 64);
        }
    };

    const int NK = K >> 5;            // 32 K-steps
    STAGE(0, 0);
    STAGE(1, 32);

    for (int k = 0; k < NK; ++k) {
        if (k < NK - 1) {
            if constexpr (PER_STAGE == 4) asm volatile("s_waitcnt vmcnt(4)" ::: "memory");
            else                          asm volatile("s_waitcnt vmcnt(3)" ::: "memory");
        } else {
            asm volatile("s_waitcnt vmcnt(0)" ::: "memory");
        }
        __builtin_amdgcn_s_barrier();
        __builtin_amdgcn_sched_barrier(0);
        if (k + 2 < NK) STAGE((k + 2) % 3, (k + 2) << 5);

        const unsigned short* as = SM + (k % 3) * (BM + BN) * 32;
        const unsigned short* bs = as + BM * 32;
        bf16x8 af[FM], bfr[FN];
#pragma unroll
        for (int m = 0; m < FM; ++m)
            af[m] = *(const bf16x8*)(as + (waveM + m * 16 + l15) * 32 + lhi * 8);
#pragma unroll
        for (int n = 0; n < FN; ++n)
            bfr[n] = *(const bf16x8*)(bs + (waveN + n * 16 + l15) * 32 + lhi * 8);
        __builtin_amdgcn_s_setprio(1);
#pragma unroll
        for (int m = 0; m < FM; ++m)
#pragma unroll
            for (int n = 0; n < FN; ++n)
                acc[m][n] = __builtin_amdgcn_mfma_f32_16x16x32_bf16(af[m], bfr[n], acc[m][n], 0, 0, 0);
        __builtin_amdgcn_s_setprio(0);
    }

    if constexpr (MODE == 0) {
#pragma unroll
        for (int n = 0; n < FN; ++n) {
            int col = n0 + waveN + n * 16 + l15;
#pragma unroll
            for (int m = 0; m < FM; ++m) {
                int rowb = m0 + waveM + m * 16 + (lhi << 2);
#pragma unroll
                for (int r = 0; r < 4; ++r)
                    outF[(size_t)(rowb + r) * D_MODEL + col] = acc[m][n][r];
            }
        }
    } else {
        __syncthreads();  // all waves done with stage buffers before aliasing
        unsigned short* Ct = ((unsigned short*)SM) + wid * 4608;  // 64x72/wave
        const int colg0 = n0 + waveN;
        const int hh    = (colg0 >> 6) & (NH - 1);
        const int rowg0 = m0 + waveM;
        const int bb    = rowg0 >> 11;
        const size_t bhh = (size_t)(bb * NH + hh);

#pragma unroll
        for (int n = 0; n < 4; ++n) {
            int cl = n * 16 + l15;
#pragma unroll
            for (int m = 0; m < 4; ++m) {
#pragma unroll
                for (int r = 0; r < 4; ++r) {
                    float v  = acc[m][n][r];
                    float pv = __shfl_xor(v, 1);
                    int rl = m * 16 + (lhi << 2) + r;
                    if (z == 2) {
                        Ct[cl * 72 + rl] = f2bf(v);
                    } else {
                        int ss = (rowg0 + rl) & (SEQ - 1);
                        float2 cs = tab[(ss << 5) + (cl >> 1)];
                        float o = (cl & 1) ? (pv * cs.y + v * cs.x)
                                           : (v * cs.x - pv * cs.y);
                        if (z == 0) o *= 0.18033688011f;  // (1/8)*log2(e)
                        Ct[rl * 72 + cl] = f2bf(o);
                    }
                }
            }
        }
        asm volatile("s_waitcnt lgkmcnt(0)" ::: "memory");

        const int lr = lane >> 3;
        const int lc = (lane & 7) << 3;
#pragma unroll
        for (int i = 0; i < 8; ++i) {
            int rl = i * 8 + lr;
            uint4 w = *(const uint4*)&Ct[rl * 72 + lc];
            if (z == 2) {
                int ss0 = rowg0 & (SEQ - 1);
                *(uint4*)(Vt + (bhh * DK + rl) * SEQ + ss0 + lc) = w;
            } else {
                int ss = (rowg0 + rl) & (SEQ - 1);
                unsigned short* dst = (z == 0) ? Qh : Kh;
                *(uint4*)(dst + (bhh * SEQ + ss) * DK + lc) = w;
            }
        }
    }
}

// ---------------------------------------------------------------------------
// causal flash attention v7: UNPAIRED, 1024 one-q-tile blocks (4 blocks/CU;
// R8's paired 512-block grid capped occupancy at 2 blocks/CU by COUNT).
// Launch-index map gives each XCD 4 contiguous bh (K/V 2MB, L2-resident) and
// makes the 4 co-resident blocks per CU share bh with qt's from different
// quartiles summing ~constant (work balance):
//   xcd=B&7, r=B>>3: bh=(xcd<<2)|(r&3); yq=r>>2; g=yq>>3, j=yq&7;
//   qt = g*8 + (g odd ? 7-j : j)   (co-resident qt sum == 62 for all CUs)
// Rest unchanged: KV tile 64, gload_lds dbuf, both-sides XOR swizzle,
// cvt_pk P packing, defer-max, one vmcnt(0)+barrier per kv-iter.
// ---------------------------------------------------------------------------
__global__ __launch_bounds__(256) void attn_kernel(
    const unsigned short* __restrict__ Qh,
    const unsigned short* __restrict__ Kh,
    const unsigned short* __restrict__ Vt,
    unsigned short* __restrict__ O)
{
    __shared__ unsigned short Ks[2][64 * 64];
    __shared__ unsigned short Vs[2][64 * 64];
    __shared__ unsigned short P[4][16 * 64];

    const int tid  = threadIdx.x;
    const int lane = tid & 63;
    const int wid  = tid >> 6;
    const int l15 = lane & 15, lhi = lane >> 4;

    const int Bk  = blockIdx.x;
    const int xcd = Bk & 7;
    const int r0  = Bk >> 3;
    const int bh  = (xcd << 2) | (r0 & 3);
    const int yq  = r0 >> 2;
    const int g   = yq >> 3, j = yq & 7;
    const int qt  = (g << 3) + ((g & 1) ? (7 - j) : j);
    const int b = bh >> 4, h = bh & 15;

    const unsigned short* Qb = Qh + (size_t)bh * SEQ * DK;
    const unsigned short* Kb = Kh + (size_t)bh * SEQ * DK;
    const unsigned short* Vb = Vt + (size_t)bh * DK * SEQ;

    auto STAGE = [&](int buf, int kv0s) {
#pragma unroll
        for (int c = 0; c < 2; ++c) {
            int ub = c * 256 + wid * 64;
            int u  = ub + lane;
            int kr = u >> 3;
            int kc = (u & 7) ^ (kr & 7);
            gload16(Kb + (size_t)(kv0s + kr) * DK + kc * 8, &Ks[buf][(size_t)ub * 8]);
        }
#pragma unroll
        for (int c = 0; c < 2; ++c) {
            int ub = c * 256 + wid * 64;
            int u  = ub + lane;
            int vr = u >> 3;
            int vc = (u & 7) ^ (vr & 7);
            gload16(Vb + (size_t)vr * SEQ + kv0s + vc * 8, &Vs[buf][(size_t)ub * 8]);
        }
    };

    const f32x4 zero = {0.f, 0.f, 0.f, 0.f};
    const f32x4 ninf = {-1e30f, -1e30f, -1e30f, -1e30f};

    STAGE(0, 0);
    int cur = 0;

    const int q0 = qt * 64;
    const int qw = q0 + wid * 16;

    bf16x8 qf[2];
#pragma unroll
    for (int kk = 0; kk < 2; ++kk)
        qf[kk] = *(const bf16x8*)(Qb + (size_t)(qw + l15) * DK + kk * 32 + lhi * 8);

    f32x4 oacc[4];
#pragma unroll
    for (int nd = 0; nd < 4; ++nd) oacc[nd] = zero;
    float mrow = -1e30f;
    float lrow = 0.f;

    for (int kt = 0; kt <= qt; ++kt) {
        const int kv0 = kt << 6;
        const bool diag = (kt == qt);
        const int nlim = diag ? (wid + 1) : 4;

        asm volatile("s_waitcnt vmcnt(0)" ::: "memory");
        __builtin_amdgcn_s_barrier();
        __builtin_amdgcn_sched_barrier(0);

        if (kt < qt) STAGE(cur ^ 1, kv0 + 64);

        f32x4 s[4];
#pragma unroll
        for (int n = 0; n < 4; ++n) s[n] = (n < nlim) ? zero : ninf;

        const int sw = l15 & 7;
        __builtin_amdgcn_s_setprio(1);
#pragma unroll
        for (int n = 0; n < 4; ++n) {
            if (n < nlim) {
                int rr = n * 16 + l15;
                bf16x8 k0 = *(const bf16x8*)&Ks[cur][rr * 64 + ((lhi ^ sw) << 3)];
                bf16x8 k1 = *(const bf16x8*)&Ks[cur][rr * 64 + (((4 + lhi) ^ sw) << 3)];
                s[n] = __builtin_amdgcn_mfma_f32_16x16x32_bf16(k0, qf[0], s[n], 0, 0, 0);
                s[n] = __builtin_amdgcn_mfma_f32_16x16x32_bf16(k1, qf[1], s[n], 0, 0, 0);
            }
        }
        __builtin_amdgcn_s_setprio(0);

        if (diag) {
            const int qg = qw + l15;
#pragma unroll
            for (int n = 0; n < 4; ++n) {
                if (n < nlim) {
#pragma unroll
                    for (int rr = 0; rr < 4; ++rr) {
                        int kg = kv0 + n * 16 + (lhi << 2) + rr;
                        if (kg > qg) s[n][rr] = -1e30f;
                    }
                }
            }
        }

        float mx = fmaxf(fmaxf(s[0][0], s[0][1]), fmaxf(s[0][2], s[0][3]));
#pragma unroll
        for (int n = 1; n < 4; ++n)
            mx = fmaxf(mx, fmaxf(fmaxf(s[n][0], s[n][1]), fmaxf(s[n][2], s[n][3])));
        mx = fmaxf(mx, __shfl_xor(mx, 16));
        mx = fmaxf(mx, __shfl_xor(mx, 32));

        float alpha = 1.f;
        const int allDefer = __all(mx <= mrow + 8.f);
        if (!allDefer) {
            float mn = fmaxf(mrow, mx);
            alpha = __builtin_amdgcn_exp2f(mrow - mn);
            mrow = mn;
        }

#pragma unroll
        for (int n = 0; n < 4; ++n)
#pragma unroll
            for (int rr = 0; rr < 4; ++rr)
                s[n][rr] = __builtin_amdgcn_exp2f(s[n][rr] - mrow);

        float rs = 0.f;
#pragma unroll
        for (int n = 0; n < 4; ++n)
            rs += (s[n][0] + s[n][1]) + (s[n][2] + s[n][3]);
        rs += __shfl_xor(rs, 16);
        rs += __shfl_xor(rs, 32);
        lrow = allDefer ? (lrow + rs) : (lrow * alpha + rs);

#pragma unroll
        for (int n = 0; n < 4; ++n) {
            uint2 pk;
            pk.x = cvtpk(s[n][0], s[n][1]);
            pk.y = cvtpk(s[n][2], s[n][3]);
            int cW = 2 * n + (lhi >> 1);
            *(uint2*)&P[wid][(l15 << 6) + ((cW ^ sw) << 3) + ((lhi & 1) << 2)] = pk;
        }

        if (!allDefer) {
            float a0 = __shfl(alpha, (lhi << 2) + 0);
            float a1 = __shfl(alpha, (lhi << 2) + 1);
            float a2 = __shfl(alpha, (lhi << 2) + 2);
            float a3 = __shfl(alpha, (lhi << 2) + 3);
#pragma unroll
            for (int nd = 0; nd < 4; ++nd) {
                oacc[nd][0] *= a0; oacc[nd][1] *= a1;
                oacc[nd][2] *= a2; oacc[nd][3] *= a3;
            }
        }

        asm volatile("s_waitcnt lgkmcnt(0)" ::: "memory");
        const int kklim = diag ? ((nlim + 1) >> 1) : 2;
        bf16x8 pa[2];
#pragma unroll
        for (int kk = 0; kk < 2; ++kk)
            if (kk < kklim)
                pa[kk] = *(const bf16x8*)&P[wid][(l15 << 6) + ((((kk << 2) + lhi) ^ sw) << 3)];

        __builtin_amdgcn_s_setprio(1);
#pragma unroll
        for (int nd = 0; nd < 4; ++nd)
#pragma unroll
            for (int kk = 0; kk < 2; ++kk)
                if (kk < kklim) {
                    int rd = nd * 16 + l15;
                    bf16x8 vf = *(const bf16x8*)&Vs[cur][rd * 64 + ((((kk << 2) + lhi) ^ sw) << 3)];
                    oacc[nd] = __builtin_amdgcn_mfma_f32_16x16x32_bf16(pa[kk], vf, oacc[nd], 0, 0, 0);
                }
        __builtin_amdgcn_s_setprio(0);

        cur ^= 1;
    }

    float inv = 1.f / lrow;
    float i0 = __shfl(inv, (lhi << 2) + 0);
    float i1 = __shfl(inv, (lhi << 2) + 1);
    float i2 = __shfl(inv, (lhi << 2) + 2);
    float i3 = __shfl(inv, (lhi << 2) + 3);
#pragma unroll
    for (int nd = 0; nd < 4; ++nd) {
        int d = nd * 16 + l15;
        int rowb = qw + (lhi << 2);
        O[((size_t)(b * SEQ + rowb + 0)) * D_MODEL + h * DK + d] = f2bf(oacc[nd][0] * i0);
        O[((size_t)(b * SEQ + rowb + 1)) * D_MODEL + h * DK + d] = f2bf(oacc[nd][1] * i1);
        O[((size_t)(b * SEQ + rowb + 2)) * D_MODEL + h * DK + d] = f2bf(oacc[nd][2] * i2);
        O[((size_t)(b * SEQ + rowb + 3)) * D_MODEL + h * DK + d] = f2bf(oacc[nd][3] * i3);
    }
}

// ---------------------------------------------------------------------------
extern "C" void kernel_launch(void* const* d_in, const int* in_sizes, int n_in,
                              void* d_out, int out_size, void* d_ws, size_t ws_size,
                              hipStream_t stream)
{
    const float* x  = (const float*)d_in[0];
    const float* Wq = (const float*)d_in[1];
    const float* Wk = (const float*)d_in[2];
    const float* Wv = (const float*)d_in[3];
    const float* Wo = (const float*)d_in[4];
    float* out = (float*)d_out;

    char* ws = (char*)d_ws;
    unsigned short* xb  = (unsigned short*)(ws);                    // 8 MB (reused as attn buf)
    unsigned short* Wqb = (unsigned short*)(ws + ( 8ull << 20));
    unsigned short* Wkb = (unsigned short*)(ws + (10ull << 20));
    unsigned short* Wvb = (unsigned short*)(ws + (12ull << 20));
    unsigned short* Wob = (unsigned short*)(ws + (14ull << 20));
    unsigned short* Qh  = (unsigned short*)(ws + (16ull << 20));    // [bh][s][64]
    unsigned short* Kh  = (unsigned short*)(ws + (24ull << 20));    // [bh][s][64]
    unsigned short* Vt  = (unsigned short*)(ws + (32ull << 20));    // [bh][64][s]
    float2*         tab = (float2*)(ws + (40ull << 20));            // 512 KB RoPE table
    unsigned short* attn = xb;

    cast5<<<dim3(512, 6), 256, 0, stream>>>(x, Wq, Wk, Wv, Wo, xb, Wqb, Wkb, Wvb, Wob, tab);

    gemm_bt<1, 128, 128><<<768, 256, 0, stream>>>(
        xb, Wqb, Wkb, Wvb, nullptr, Qh, Kh, Vt, tab, NB * SEQ, D_MODEL);

    attn_kernel<<<1024, 256, 0, stream>>>(Qh, Kh, Vt, attn);

    gemm_bt<0, 64, 128><<<512, 256, 0, stream>>>(
        attn, Wob, Wob, Wob, out, nullptr, nullptr, nullptr, nullptr, NB * SEQ, D_MODEL);
}

// Round 10
// 115.926 us; speedup vs baseline: 1.7749x; 1.0067x over previous
//
#include <hip/hip_runtime.h>

typedef float f32x4 __attribute__((ext_vector_type(4)));
typedef __bf16 bf16x8 __attribute__((ext_vector_type(8)));

#define D_MODEL 1024
#define SEQ     2048
#define NB      2
#define NH      16
#define DK      64

__device__ __forceinline__ unsigned short f2bf(float f) {
    union { float f; unsigned int u; } un; un.f = f;
    unsigned int r = un.u + 0x7fffu + ((un.u >> 16) & 1u);
    return (unsigned short)(r >> 16);
}

__device__ __forceinline__ unsigned cvtpk(float lo, float hi) {
    unsigned r;
    asm("v_cvt_pk_bf16_f32 %0, %1, %2" : "=v"(r) : "v"(lo), "v"(hi));
    return r;
}

__device__ __forceinline__ void gload16(const void* g, void* l) {
    __builtin_amdgcn_global_load_lds((__attribute__((address_space(1))) void*)g,
                                     (__attribute__((address_space(3))) void*)l,
                                     16, 0, 0);
}

// ---------------------------------------------------------------------------
// fused fp32 -> bf16 casts for x and the 4 weights + RoPE cos/sin table
// ---------------------------------------------------------------------------
__global__ __launch_bounds__(256) void cast5(
    const float* __restrict__ x,  const float* __restrict__ wq,
    const float* __restrict__ wk, const float* __restrict__ wv,
    const float* __restrict__ wo,
    unsigned short* __restrict__ xb,  unsigned short* __restrict__ wqb,
    unsigned short* __restrict__ wkb, unsigned short* __restrict__ wvb,
    unsigned short* __restrict__ wob, float2* __restrict__ tab)
{
    if (blockIdx.y == 5) {  // RoPE table: [ss][p] -> (cos, sin), p = d/2 index
        int idx = blockIdx.x * 256 + threadIdx.x;
        if (idx < SEQ * 32) {
            int ss = idx >> 5, p = idx & 31;
            float freq = exp2f(-0.41524101186f * (float)p);  // 10000^(-p/32)
            float sn, cs;
            sincosf((float)ss * freq, &sn, &cs);
            tab[idx] = make_float2(cs, sn);
        }
        return;
    }
    const float* src; unsigned short* dst; int n8;
    switch (blockIdx.y) {
        case 0:  src = x;  dst = xb;  n8 = (NB*SEQ*D_MODEL)/8; break;
        case 1:  src = wq; dst = wqb; n8 = (D_MODEL*D_MODEL)/8; break;
        case 2:  src = wk; dst = wkb; n8 = (D_MODEL*D_MODEL)/8; break;
        case 3:  src = wv; dst = wvb; n8 = (D_MODEL*D_MODEL)/8; break;
        default: src = wo; dst = wob; n8 = (D_MODEL*D_MODEL)/8; break;
    }
    int stride = gridDim.x * blockDim.x;
    for (int i = blockIdx.x * blockDim.x + threadIdx.x; i < n8; i += stride) {
        const float4* p = (const float4*)src + (size_t)i * 2;
        float4 a = p[0], b = p[1];
        union { unsigned short h[8]; uint4 v; } u;
        u.h[0] = f2bf(a.x); u.h[1] = f2bf(a.y); u.h[2] = f2bf(a.z); u.h[3] = f2bf(a.w);
        u.h[4] = f2bf(b.x); u.h[5] = f2bf(b.y); u.h[6] = f2bf(b.z); u.h[7] = f2bf(b.w);
        ((uint4*)dst)[i] = u.v;
    }
}

// ---------------------------------------------------------------------------
// GEMM  C[M][1024] = A[M][K](bf16) * B[1024][K]^T (bf16, weights are [out][in])
// Triple-buffered LDS + 2-deep prefetch + counted vmcnt. A-panel XCD
// clustering via 1-D launch remap (L%8 == y%8).
// MODE 0 (BM=64, BN=128): plain fp32 write to outF
// MODE 1 (BM=BN=128): QKV fused, RoPE epilogue via LDS.
// ---------------------------------------------------------------------------
template <int MODE, int BM, int BN>
__global__ __launch_bounds__(256) void gemm_bt(
    const unsigned short* __restrict__ A,
    const unsigned short* __restrict__ B0,
    const unsigned short* __restrict__ B1,
    const unsigned short* __restrict__ B2,
    float* __restrict__ outF,
    unsigned short* __restrict__ Qh,
    unsigned short* __restrict__ Kh,
    unsigned short* __restrict__ Vt,
    const float2* __restrict__ tab,
    int M, int K)
{
    constexpr int PER_STAGE = (BM + BN) / 64;   // gload16 per thread per stage
    constexpr int WM = BM / 2, WN = BN / 2;
    constexpr int FM = WM / 16, FN = WN / 16;
    __shared__ __align__(16) unsigned short SM[3 * (BM + BN) * 32];

    const int lane = threadIdx.x & 63;
    const int wid  = threadIdx.x >> 6;
    const int l15 = lane & 15, lhi = lane >> 4;

    // ---- block swizzle decode: L = (y&7) + 8*(x + 8*(y>>3) + 32*z) ----
    const int L  = blockIdx.x;
    const int yl = L & 7;
    const int t  = L >> 3;
    const int bx = t & 7;
    const int t2 = t >> 3;
    int y, z;
    if constexpr (MODE == 1) { y = ((t2 & 3) << 3) | yl; z = t2 >> 2; }
    else                     { y = (t2 << 3) | yl;       z = 0;       }
    const int m0 = y * BM;
    const int n0 = bx * BN;
    const unsigned short* B = (z == 0) ? B0 : (z == 1) ? B1 : B2;
    const int waveM = (wid >> 1) * WM;
    const int waveN = (wid & 1) * WN;

    f32x4 acc[FM][FN];
    f32x4 zero = {0.f, 0.f, 0.f, 0.f};
#pragma unroll
    for (int m = 0; m < FM; ++m)
#pragma unroll
        for (int n = 0; n < FN; ++n) acc[m][n] = zero;

    const int lrow = lane >> 2;       // row within 16-row staging chunk
    const int lcol = (lane & 3) * 8;  // element offset within row

    auto STAGE = [&](int buf, int k0) {
        unsigned short* as = SM + buf * (BM + BN) * 32;
        unsigned short* bs = as + BM * 32;
#pragma unroll
        for (int q = 0; q < BM / 64; ++q) {
            int rbase = wid * (BM / 4) + q * 16;
            gload16(A + (size_t)(m0 + rbase + lrow) * K + k0 + lcol,
                    (char*)as + rbase * 64);
        }
#pragma unroll
        for (int q = 0; q < BN / 64; ++q) {
            int rbase = wid * (BN / 4) + q * 16;
            gload16(B + (size_t)(n0 + rbase + lrow) * K + k0 + lcol,
                    (char*)bs + rbase * 64);
        }
    };

    const int NK = K >> 5;            // 32 K-steps
    STAGE(0, 0);
    STAGE(1, 32);

    for (int k = 0; k < NK; ++k) {
        if (k < NK - 1) {
            if constexpr (PER_STAGE == 4) asm volatile("s_waitcnt vmcnt(4)" ::: "memory");
            else                          asm volatile("s_waitcnt vmcnt(3)" ::: "memory");
        } else {
            asm volatile("s_waitcnt vmcnt(0)" ::: "memory");
        }
        __builtin_amdgcn_s_barrier();
        __builtin_amdgcn_sched_barrier(0);
        if (k + 2 < NK) STAGE((k + 2) % 3, (k + 2) << 5);

        const unsigned short* as = SM + (k % 3) * (BM + BN) * 32;
        const unsigned short* bs = as + BM * 32;
        bf16x8 af[FM], bfr[FN];
#pragma unroll
        for (int m = 0; m < FM; ++m)
            af[m] = *(const bf16x8*)(as + (waveM + m * 16 + l15) * 32 + lhi * 8);
#pragma unroll
        for (int n = 0; n < FN; ++n)
            bfr[n] = *(const bf16x8*)(bs + (waveN + n * 16 + l15) * 32 + lhi * 8);
        __builtin_amdgcn_s_setprio(1);
#pragma unroll
        for (int m = 0; m < FM; ++m)
#pragma unroll
            for (int n = 0; n < FN; ++n)
                acc[m][n] = __builtin_amdgcn_mfma_f32_16x16x32_bf16(af[m], bfr[n], acc[m][n], 0, 0, 0);
        __builtin_amdgcn_s_setprio(0);
    }

    if constexpr (MODE == 0) {
#pragma unroll
        for (int n = 0; n < FN; ++n) {
            int col = n0 + waveN + n * 16 + l15;
#pragma unroll
            for (int m = 0; m < FM; ++m) {
                int rowb = m0 + waveM + m * 16 + (lhi << 2);
#pragma unroll
                for (int r = 0; r < 4; ++r)
                    outF[(size_t)(rowb + r) * D_MODEL + col] = acc[m][n][r];
            }
        }
    } else {
        __syncthreads();  // all waves done with stage buffers before aliasing
        unsigned short* Ct = ((unsigned short*)SM) + wid * 4608;  // 64x72/wave
        const int colg0 = n0 + waveN;
        const int hh    = (colg0 >> 6) & (NH - 1);
        const int rowg0 = m0 + waveM;
        const int bb    = rowg0 >> 11;
        const size_t bhh = (size_t)(bb * NH + hh);

#pragma unroll
        for (int n = 0; n < 4; ++n) {
            int cl = n * 16 + l15;
#pragma unroll
            for (int m = 0; m < 4; ++m) {
#pragma unroll
                for (int r = 0; r < 4; ++r) {
                    float v  = acc[m][n][r];
                    float pv = __shfl_xor(v, 1);
                    int rl = m * 16 + (lhi << 2) + r;
                    if (z == 2) {
                        Ct[cl * 72 + rl] = f2bf(v);
                    } else {
                        int ss = (rowg0 + rl) & (SEQ - 1);
                        float2 cs = tab[(ss << 5) + (cl >> 1)];
                        float o = (cl & 1) ? (pv * cs.y + v * cs.x)
                                           : (v * cs.x - pv * cs.y);
                        if (z == 0) o *= 0.18033688011f;  // (1/8)*log2(e)
                        Ct[rl * 72 + cl] = f2bf(o);
                    }
                }
            }
        }
        asm volatile("s_waitcnt lgkmcnt(0)" ::: "memory");

        const int lr = lane >> 3;
        const int lc = (lane & 7) << 3;
#pragma unroll
        for (int i = 0; i < 8; ++i) {
            int rl = i * 8 + lr;
            uint4 w = *(const uint4*)&Ct[rl * 72 + lc];
            if (z == 2) {
                int ss0 = rowg0 & (SEQ - 1);
                *(uint4*)(Vt + (bhh * DK + rl) * SEQ + ss0 + lc) = w;
            } else {
                int ss = (rowg0 + rl) & (SEQ - 1);
                unsigned short* dst = (z == 0) ? Qh : Kh;
                *(uint4*)(dst + (bhh * SEQ + ss) * DK + lc) = w;
            }
        }
    }
}

// ---------------------------------------------------------------------------
// causal flash attention v8: paired + sustained-resident + counted vmcnt.
//  - 512 blocks (4 waves): pair (pi, 31-pi) of 64-row q-tiles -> EXACTLY 33
//    kv-iters per block (uniform; fixes R9's occupancy decay to 24%)
//  - LDS 56 KB -> exactly 2 blocks/CU co-resident = 16 waves/CU sustained
//  - CU map: blocks L and L+256 land on same CU, share bh (K/V L2-resident
//    per XCD: 4 bh x 512 KB = 2 MB); qt pairs {q,31-q},{q+8,23-q}
//  - 3-buffer, 2-AHEAD prefetch, vmcnt(4) in main loop (never 0 until the
//    final tile; T4) -> each tile's loads get ~2 compute phases to land
//  - body unchanged: both-sides XOR swizzle, cvt_pk P, defer-max, swapped QK
// ---------------------------------------------------------------------------
__global__ __launch_bounds__(256) void attn_kernel(
    const unsigned short* __restrict__ Qh,
    const unsigned short* __restrict__ Kh,
    const unsigned short* __restrict__ Vt,
    unsigned short* __restrict__ O)
{
    __shared__ unsigned short Ks[3][64 * 64];   // 8 KB x3
    __shared__ unsigned short Vs[3][64 * 64];   // 8 KB x3
    __shared__ unsigned short P[4][16 * 64];    // 8 KB

    const int tid  = threadIdx.x;
    const int lane = tid & 63;
    const int wid  = tid >> 6;
    const int l15 = lane & 15, lhi = lane >> 4;

    const int L   = blockIdx.x;
    const int xcd = L & 7;
    const int r0  = L >> 3;              // 0..63
    const int bh  = (xcd << 2) | (r0 & 3);
    const int pi  = r0 >> 2;             // 0..15
    const int b = bh >> 4, h = bh & 15;

    const unsigned short* Qb = Qh + (size_t)bh * SEQ * DK;
    const unsigned short* Kb = Kh + (size_t)bh * SEQ * DK;
    const unsigned short* Vb = Vt + (size_t)bh * DK * SEQ;

    const int NT0 = pi + 1;              // iters in phase 0
    const int NTT = 33;                  // total iters (uniform for all blocks)

    auto kv_of = [&](int g) { return (g < NT0 ? g : g - NT0) << 6; };

    auto STAGE = [&](int buf, int kv0s) {
#pragma unroll
        for (int c = 0; c < 2; ++c) {
            int ub = c * 256 + wid * 64;
            int u  = ub + lane;
            int kr = u >> 3;
            int kc = (u & 7) ^ (kr & 7);
            gload16(Kb + (size_t)(kv0s + kr) * DK + kc * 8, &Ks[buf][(size_t)ub * 8]);
            gload16(Vb + (size_t)kr * SEQ + kv0s + kc * 8, &Vs[buf][(size_t)ub * 8]);
        }
    };

    const f32x4 zero = {0.f, 0.f, 0.f, 0.f};
    const f32x4 ninf = {-1e30f, -1e30f, -1e30f, -1e30f};
    const int sw = l15 & 7;

    STAGE(0, 0);
    STAGE(1, kv_of(1));
    int g = 0;

    for (int ph = 0; ph < 2; ++ph) {
        const int qt = ph ? (31 - pi) : pi;
        const int q0 = qt << 6;
        const int qw = q0 + wid * 16;
        const int lastkt = qt;

        bf16x8 qf[2];
#pragma unroll
        for (int kk = 0; kk < 2; ++kk)
            qf[kk] = *(const bf16x8*)(Qb + (size_t)(qw + l15) * DK + kk * 32 + lhi * 8);

        f32x4 oacc[4];
#pragma unroll
        for (int nd = 0; nd < 4; ++nd) oacc[nd] = zero;
        float mrow = -1e30f;
        float lrow = 0.f;

        for (int kt = 0; kt <= lastkt; ++kt, ++g) {
            const int kv0 = kt << 6;
            const bool diag = (kt == lastkt);
            const int nlim = diag ? (wid + 1) : 4;

            if (g < NTT - 1) asm volatile("s_waitcnt vmcnt(4)" ::: "memory");
            else             asm volatile("s_waitcnt vmcnt(0)" ::: "memory");
            __builtin_amdgcn_s_barrier();
            __builtin_amdgcn_sched_barrier(0);
            if (g + 2 < NTT) STAGE((g + 2) % 3, kv_of(g + 2));

            const unsigned short* Kc = Ks[g % 3];
            const unsigned short* Vc = Vs[g % 3];

            f32x4 s[4];
#pragma unroll
            for (int n = 0; n < 4; ++n) s[n] = (n < nlim) ? zero : ninf;

            __builtin_amdgcn_s_setprio(1);
#pragma unroll
            for (int n = 0; n < 4; ++n) {
                if (n < nlim) {
                    int rr = n * 16 + l15;
                    bf16x8 k0 = *(const bf16x8*)&Kc[rr * 64 + ((lhi ^ sw) << 3)];
                    bf16x8 k1 = *(const bf16x8*)&Kc[rr * 64 + (((4 + lhi) ^ sw) << 3)];
                    s[n] = __builtin_amdgcn_mfma_f32_16x16x32_bf16(k0, qf[0], s[n], 0, 0, 0);
                    s[n] = __builtin_amdgcn_mfma_f32_16x16x32_bf16(k1, qf[1], s[n], 0, 0, 0);
                }
            }
            __builtin_amdgcn_s_setprio(0);

            if (diag) {
                const int qg = qw + l15;
#pragma unroll
                for (int n = 0; n < 4; ++n) {
                    if (n < nlim) {
#pragma unroll
                        for (int rr = 0; rr < 4; ++rr) {
                            int kg = kv0 + n * 16 + (lhi << 2) + rr;
                            if (kg > qg) s[n][rr] = -1e30f;
                        }
                    }
                }
            }

            float mx = fmaxf(fmaxf(s[0][0], s[0][1]), fmaxf(s[0][2], s[0][3]));
#pragma unroll
            for (int n = 1; n < 4; ++n)
                mx = fmaxf(mx, fmaxf(fmaxf(s[n][0], s[n][1]), fmaxf(s[n][2], s[n][3])));
            mx = fmaxf(mx, __shfl_xor(mx, 16));
            mx = fmaxf(mx, __shfl_xor(mx, 32));

            float alpha = 1.f;
            const int allDefer = __all(mx <= mrow + 8.f);
            if (!allDefer) {
                float mn = fmaxf(mrow, mx);
                alpha = __builtin_amdgcn_exp2f(mrow - mn);
                mrow = mn;
            }

#pragma unroll
            for (int n = 0; n < 4; ++n)
#pragma unroll
                for (int rr = 0; rr < 4; ++rr)
                    s[n][rr] = __builtin_amdgcn_exp2f(s[n][rr] - mrow);

            float rs = 0.f;
#pragma unroll
            for (int n = 0; n < 4; ++n)
                rs += (s[n][0] + s[n][1]) + (s[n][2] + s[n][3]);
            rs += __shfl_xor(rs, 16);
            rs += __shfl_xor(rs, 32);
            lrow = allDefer ? (lrow + rs) : (lrow * alpha + rs);

#pragma unroll
            for (int n = 0; n < 4; ++n) {
                uint2 pk;
                pk.x = cvtpk(s[n][0], s[n][1]);
                pk.y = cvtpk(s[n][2], s[n][3]);
                int cW = 2 * n + (lhi >> 1);
                *(uint2*)&P[wid][(l15 << 6) + ((cW ^ sw) << 3) + ((lhi & 1) << 2)] = pk;
            }

            if (!allDefer) {
                float a0 = __shfl(alpha, (lhi << 2) + 0);
                float a1 = __shfl(alpha, (lhi << 2) + 1);
                float a2 = __shfl(alpha, (lhi << 2) + 2);
                float a3 = __shfl(alpha, (lhi << 2) + 3);
#pragma unroll
                for (int nd = 0; nd < 4; ++nd) {
                    oacc[nd][0] *= a0; oacc[nd][1] *= a1;
                    oacc[nd][2] *= a2; oacc[nd][3] *= a3;
                }
            }

            asm volatile("s_waitcnt lgkmcnt(0)" ::: "memory");
            const int kklim = diag ? ((nlim + 1) >> 1) : 2;
            bf16x8 pa[2];
#pragma unroll
            for (int kk = 0; kk < 2; ++kk)
                if (kk < kklim)
                    pa[kk] = *(const bf16x8*)&P[wid][(l15 << 6) + ((((kk << 2) + lhi) ^ sw) << 3)];

            __builtin_amdgcn_s_setprio(1);
#pragma unroll
            for (int nd = 0; nd < 4; ++nd)
#pragma unroll
                for (int kk = 0; kk < 2; ++kk)
                    if (kk < kklim) {
                        int rd = nd * 16 + l15;
                        bf16x8 vf = *(const bf16x8*)&Vc[rd * 64 + ((((kk << 2) + lhi) ^ sw) << 3)];
                        oacc[nd] = __builtin_amdgcn_mfma_f32_16x16x32_bf16(pa[kk], vf, oacc[nd], 0, 0, 0);
                    }
            __builtin_amdgcn_s_setprio(0);
        }

        float inv = 1.f / lrow;
        float i0 = __shfl(inv, (lhi << 2) + 0);
        float i1 = __shfl(inv, (lhi << 2) + 1);
        float i2 = __shfl(inv, (lhi << 2) + 2);
        float i3 = __shfl(inv, (lhi << 2) + 3);
#pragma unroll
        for (int nd = 0; nd < 4; ++nd) {
            int d = nd * 16 + l15;
            int rowb = qw + (lhi << 2);
            O[((size_t)(b * SEQ + rowb + 0)) * D_MODEL + h * DK + d] = f2bf(oacc[nd][0] * i0);
            O[((size_t)(b * SEQ + rowb + 1)) * D_MODEL + h * DK + d] = f2bf(oacc[nd][1] * i1);
            O[((size_t)(b * SEQ + rowb + 2)) * D_MODEL + h * DK + d] = f2bf(oacc[nd][2] * i2);
            O[((size_t)(b * SEQ + rowb + 3)) * D_MODEL + h * DK + d] = f2bf(oacc[nd][3] * i3);
        }
    }
}

// ---------------------------------------------------------------------------
extern "C" void kernel_launch(void* const* d_in, const int* in_sizes, int n_in,
                              void* d_out, int out_size, void* d_ws, size_t ws_size,
                              hipStream_t stream)
{
    const float* x  = (const float*)d_in[0];
    const float* Wq = (const float*)d_in[1];
    const float* Wk = (const float*)d_in[2];
    const float* Wv = (const float*)d_in[3];
    const float* Wo = (const float*)d_in[4];
    float* out = (float*)d_out;

    char* ws = (char*)d_ws;
    unsigned short* xb  = (unsigned short*)(ws);                    // 8 MB (reused as attn buf)
    unsigned short* Wqb = (unsigned short*)(ws + ( 8ull << 20));
    unsigned short* Wkb = (unsigned short*)(ws + (10ull << 20));
    unsigned short* Wvb = (unsigned short*)(ws + (12ull << 20));
    unsigned short* Wob = (unsigned short*)(ws + (14ull << 20));
    unsigned short* Qh  = (unsigned short*)(ws + (16ull << 20));    // [bh][s][64]
    unsigned short* Kh  = (unsigned short*)(ws + (24ull << 20));    // [bh][s][64]
    unsigned short* Vt  = (unsigned short*)(ws + (32ull << 20));    // [bh][64][s]
    float2*         tab = (float2*)(ws + (40ull << 20));            // 512 KB RoPE table
    unsigned short* attn = xb;

    cast5<<<dim3(512, 6), 256, 0, stream>>>(x, Wq, Wk, Wv, Wo, xb, Wqb, Wkb, Wvb, Wob, tab);

    gemm_bt<1, 128, 128><<<768, 256, 0, stream>>>(
        xb, Wqb, Wkb, Wvb, nullptr, Qh, Kh, Vt, tab, NB * SEQ, D_MODEL);

    attn_kernel<<<512, 256, 0, stream>>>(Qh, Kh, Vt, attn);

    gemm_bt<0, 64, 128><<<512, 256, 0, stream>>>(
        attn, Wob, Wob, Wob, out, nullptr, nullptr, nullptr, nullptr, NB * SEQ, D_MODEL);
}